// Round 4
// baseline (283.832 us; speedup 1.0000x reference)
//
#include <hip/hip_runtime.h>
#include <stdint.h>
#include <stddef.h>

#define DEVINL __device__ __forceinline__

typedef unsigned short u16;
typedef unsigned int u32;
typedef __attribute__((ext_vector_type(8))) short short8;
typedef __attribute__((ext_vector_type(4))) float f32x4;
typedef __attribute__((ext_vector_type(16))) float f32x16;
typedef __attribute__((ext_vector_type(4))) u32 u32x4;
typedef __attribute__((ext_vector_type(2))) u32 u32x2;

// log2(e)/8 : folded into W_q / b_q so flash's exp2 needs no multiply
#define QSCALE 0.18033688011112042f

// ---------- helpers ----------
DEVINL u16 f2bf(float f) {
    u32 u = __builtin_bit_cast(u32, f);
    u32 r = (u + 0x7fffu + ((u >> 16) & 1u)) >> 16;   // RNE
    return (u16)r;
}

DEVINL void gld_lds16(const void* g, void* l) {
    __builtin_amdgcn_global_load_lds(
        (__attribute__((address_space(1))) u32*)(uintptr_t)g,
        (__attribute__((address_space(3))) u32*)l, 16, 0, 0);
}

// pack two fp32 -> bf16x2 by truncation (bias cancels: denominator sums the same bf16 P)
DEVINL u32 pack_bf16_trunc(float lo, float hi) {
    return __builtin_amdgcn_perm(__builtin_bit_cast(u32, hi),
                                 __builtin_bit_cast(u32, lo), 0x07060302u);
}

// cross-lane half swap (gfx950), both outputs used:
// a' = {a[0:31], b[0:31]}, b' = {a[32:63], b[32:63]}
DEVINL void plswap32(u32 &a, u32 &b) {
#if __has_builtin(__builtin_amdgcn_permlane32_swap)
    u32x2 r = __builtin_amdgcn_permlane32_swap(a, b, false, false);
    a = r[0]; b = r[1];
#else
    asm("v_permlane32_swap_b32 %0, %1" : "+v"(a), "+v"(b));
#endif
}

// ---------- fused input prep: casts + scale folding, one launch ----------
// blocks [0,4096): x -> xb ; [4096,5632): w_qkv -> wqb (Q rows scaled)
// [5632,6144): w_o -> wob ; [6144,6156): b_qkv scale -> bsc
__global__ void prep_inputs(const float* __restrict__ x, const float* __restrict__ wqkv,
                            const float* __restrict__ bqkv, const float* __restrict__ wo,
                            u16* __restrict__ xb, u16* __restrict__ wqb,
                            u16* __restrict__ wob, float* __restrict__ bsc) {
    int blk = blockIdx.x;
    if (blk < 6144) {
        const float* src; u16* dst; int base; bool qscale = false;
        if (blk < 4096)      { src = x;    dst = xb;  base = blk; }
        else if (blk < 5632) { src = wqkv; dst = wqb; base = blk - 4096; qscale = true; }
        else                 { src = wo;   dst = wob; base = blk - 5632; }
        int i = (base * 256 + threadIdx.x) * 8;
        float sc = 1.0f;
        if (qscale) { int row = i >> 10; if ((row % 192) < 64) sc = QSCALE; }
        float4 a = *(const float4*)(src + i);
        float4 c = *(const float4*)(src + i + 4);
        union { u16 s[8]; u32x4 v; } t;
        t.s[0] = f2bf(a.x * sc); t.s[1] = f2bf(a.y * sc); t.s[2] = f2bf(a.z * sc); t.s[3] = f2bf(a.w * sc);
        t.s[4] = f2bf(c.x * sc); t.s[5] = f2bf(c.y * sc); t.s[6] = f2bf(c.z * sc); t.s[7] = f2bf(c.w * sc);
        *(u32x4*)(dst + i) = t.v;
    } else {
        int i = (blk - 6144) * 256 + threadIdx.x;   // 0..3071
        float sc = ((i % 192) < 64) ? QSCALE : 1.0f;
        bsc[i] = bqkv[i] * sc;
    }
}

// ---------- QKV GEMM  qkv[M,3072] = x[M,K] * w_qkv[3072,K]^T + b ----------
// V-section columns (col%192 in [128,192)) are written TRANSPOSED straight to
// vt[bh][d][s] (one 8B store per lane); Q/K go to qkvb. 16-col groups never
// straddle section boundaries, so the branch is wave-uniform.
__global__ void gemm_qkv(const u16* __restrict__ A, const u16* __restrict__ Bm,
                         const float* __restrict__ bias, u16* __restrict__ qkvb,
                         u16* __restrict__ vtb) {
    const int K = 1024, N = 3072;
    __shared__ u16 As[128 * 32];
    __shared__ u16 Bs[128 * 32];
    const int tid = threadIdx.x;
    const int lane = tid & 63;
    const int wv = tid >> 6, wr = wv >> 1, wc = wv & 1;
    const int l15 = lane & 15, quad = lane >> 4;
    const int m0 = blockIdx.y * 128, n0 = blockIdx.x * 128;

    f32x4 acc[4][4];
#pragma unroll
    for (int i = 0; i < 4; i++)
#pragma unroll
        for (int j = 0; j < 4; j++) acc[i][j] = (f32x4){0.f, 0.f, 0.f, 0.f};

    const u16* Ab = A + (size_t)m0 * K;
    const u16* Bb = Bm + (size_t)n0 * K;
    const int srow = tid >> 2;
    const int sc8 = (tid & 3) * 8;

    for (int k0 = 0; k0 < K; k0 += 32) {
#pragma unroll
        for (int i = 0; i < 2; i++) {
            int row = i * 64 + srow;
            gld_lds16(Ab + (size_t)row * K + k0 + sc8, (char*)As + (size_t)(i * 256 + tid) * 16);
            gld_lds16(Bb + (size_t)row * K + k0 + sc8, (char*)Bs + (size_t)(i * 256 + tid) * 16);
        }
        __syncthreads();
        short8 af[4], bf8[4];
#pragma unroll
        for (int mi = 0; mi < 4; mi++)
            af[mi] = *(const short8*)(As + (wr * 64 + mi * 16 + l15) * 32 + quad * 8);
#pragma unroll
        for (int ni = 0; ni < 4; ni++)
            bf8[ni] = *(const short8*)(Bs + (wc * 64 + ni * 16 + l15) * 32 + quad * 8);
#pragma unroll
        for (int mi = 0; mi < 4; mi++)
#pragma unroll
            for (int ni = 0; ni < 4; ni++)
                acc[mi][ni] = __builtin_amdgcn_mfma_f32_16x16x32_bf16(af[mi], bf8[ni], acc[mi][ni], 0, 0, 0);
        __syncthreads();
    }

#pragma unroll
    for (int mi = 0; mi < 4; mi++) {
        int row_b = m0 + wr * 64 + mi * 16 + quad * 4;
#pragma unroll
        for (int ni = 0; ni < 4; ni++) {
            int c0 = n0 + wc * 64 + ni * 16;          // group base (16-aligned)
            int sec0 = c0 % 192;                       // section offset, wave-uniform
            float bv = bias[c0 + l15];
            float v0 = acc[mi][ni][0] + bv;
            float v1 = acc[mi][ni][1] + bv;
            float v2 = acc[mi][ni][2] + bv;
            float v3 = acc[mi][ni][3] + bv;
            if (sec0 >= 128) {
                // V element: transpose-store to vt[bh][d][s], 4 consecutive s
                int hh = c0 / 192;
                int b = row_b >> 11;
                int s = row_b & 2047;
                int d = sec0 - 128 + l15;
                u32 lo = (u32)f2bf(v0) | ((u32)f2bf(v1) << 16);
                u32 hi = (u32)f2bf(v2) | ((u32)f2bf(v3) << 16);
                *(u32x2*)(vtb + ((size_t)((b * 16 + hh) * 64 + d)) * 2048 + s) = (u32x2){lo, hi};
            } else {
                int col = c0 + l15;
                qkvb[(size_t)(row_b + 0) * N + col] = f2bf(v0);
                qkvb[(size_t)(row_b + 1) * N + col] = f2bf(v1);
                qkvb[(size_t)(row_b + 2) * N + col] = f2bf(v2);
                qkvb[(size_t)(row_b + 3) * N + col] = f2bf(v3);
            }
        }
    }
}

// ---------- out GEMM  out[M,1024] = vals2[M,K] * w_o[1024,K]^T + b_o ----------
// 128x64 tiles -> 1024 blocks (4/CU) for occupancy; fp32 output.
__global__ void gemm_out(const u16* __restrict__ A, const u16* __restrict__ Bm,
                         const float* __restrict__ bias, float* __restrict__ C) {
    const int K = 1024, N = 1024;
    __shared__ u16 As[128 * 32];   // 8 KB
    __shared__ u16 Bs[64 * 32];    // 4 KB
    const int tid = threadIdx.x;
    const int lane = tid & 63;
    const int wv = tid >> 6, wr = wv >> 1, wc = wv & 1;
    const int l15 = lane & 15, quad = lane >> 4;
    const int m0 = blockIdx.y * 128, n0 = blockIdx.x * 64;

    f32x4 acc[4][2];
#pragma unroll
    for (int i = 0; i < 4; i++)
#pragma unroll
        for (int j = 0; j < 2; j++) acc[i][j] = (f32x4){0.f, 0.f, 0.f, 0.f};

    const u16* Ab = A + (size_t)m0 * K;
    const u16* Bb = Bm + (size_t)n0 * K;
    const int srow = tid >> 2;
    const int sc8 = (tid & 3) * 8;

    for (int k0 = 0; k0 < K; k0 += 32) {
#pragma unroll
        for (int i = 0; i < 2; i++)
            gld_lds16(Ab + (size_t)(i * 64 + srow) * K + k0 + sc8, (char*)As + (size_t)(i * 256 + tid) * 16);
        gld_lds16(Bb + (size_t)srow * K + k0 + sc8, (char*)Bs + (size_t)tid * 16);
        __syncthreads();
        short8 af[4], bf8[2];
#pragma unroll
        for (int mi = 0; mi < 4; mi++)
            af[mi] = *(const short8*)(As + (wr * 64 + mi * 16 + l15) * 32 + quad * 8);
#pragma unroll
        for (int ni = 0; ni < 2; ni++)
            bf8[ni] = *(const short8*)(Bs + (wc * 32 + ni * 16 + l15) * 32 + quad * 8);
#pragma unroll
        for (int mi = 0; mi < 4; mi++)
#pragma unroll
            for (int ni = 0; ni < 2; ni++)
                acc[mi][ni] = __builtin_amdgcn_mfma_f32_16x16x32_bf16(af[mi], bf8[ni], acc[mi][ni], 0, 0, 0);
        __syncthreads();
    }

#pragma unroll
    for (int mi = 0; mi < 4; mi++) {
        int row_b = m0 + wr * 64 + mi * 16 + quad * 4;
#pragma unroll
        for (int ni = 0; ni < 2; ni++) {
            int col = n0 + wc * 32 + ni * 16 + l15;
            float bv = bias[col];
#pragma unroll
            for (int r = 0; r < 4; r++)
                C[(size_t)(row_b + r) * N + col] = acc[mi][ni][r] + bv;
        }
    }
}

// ---------- flash attention (round-6: 32x32x16 MFMA, 2-swap P redistribution) ----------
// Per wave: 32 q rows, 64-key tiles.  S^T = K*Q^T with mfma_f32_32x32x16_bf16:
// A = K rows (row=lane&31=key, k=(lane>>5)*8+e), B = Q^T (col=lane&31=q, k=d),
// C: col=lane&31=q, row=(reg&3)+8*(reg>>2)+4*(lane>>5)=key  [m74/m101].
// q lives in lane&31 for BOTH S^T-cols and PV-A-rows -> no cross-q movement.
// Packed word j of half g holds keys kb*32 + (2j&3)+8*(j>>1)+4g + {0,1}; the
// PV A-frag for kstep t needs word w from half g=w>>1 at J=4(t&1)+2h+(w&1)
// -> swap32(pw[J0],pw[J0+2]) gives (w0,w2), swap32(pw[J0+1],pw[J0+3]) gives
// (w1,w3): 2 swaps per kstep, 8 per tile (was 16 swap ops at 16x16).
// MFMA instrs/tile: 8 QK + 4 ones + 8 PV = 20 (was 36).  K/Vt double-buffered
// via global_load_lds (linear dest + pre-swizzled source), one barrier/iter.
// ds_read rows are lane&31 -> XOR swizzle (lane&7)*8 u16, uniform 8 lanes per
// 16B-granule group (the measured-conflict-free pattern).  LDS 32 KB.
__launch_bounds__(256, 4)
__global__ void flash_attn(const u16* __restrict__ qkv, const u16* __restrict__ vt,
                           u16* __restrict__ vals2) {
    __shared__ u16 Ks[2][64 * 64];   // 2 x 8 KB: 64 keys x 64 d (swizzled)
    __shared__ u16 Vts[2][64 * 64];  // 2 x 8 KB: 64 d x 64 keys (swizzled)

    const int tid = threadIdx.x;
    const int lane = tid & 63, wv = tid >> 6;
    const int l31 = lane & 31, hf = lane >> 5;
    const int ex = (lane & 7) * 8;         // u16-unit XOR for swizzled frag reads
    const int s0 = blockIdx.x * 128;
    const int bh = blockIdx.y, b = bh >> 4, h = bh & 15;

    // Q fragments in registers: qr[ds] = Q[q = own row][d = ds*16 + hf*8 .. +8]
    // (q rows pre-scaled by log2e/8 at cast time)
    short8 qr[4];
    {
        const u16* qbase = qkv + (size_t)(b * 2048 + s0 + wv * 32 + l31) * 3072 + h * 192 + hf * 8;
#pragma unroll
        for (int ds = 0; ds < 4; ds++)
            qr[ds] = *(const short8*)(qbase + ds * 16);
    }

    f32x16 o32[2];      // [db]: col d = db*32+l31, row q = (reg&3)+8*(reg>>2)+4*hf
    f32x16 sum32;       // denominator, same q mapping, col-replicated
#pragma unroll
    for (int i = 0; i < 16; i++) { o32[0][i] = 0.f; o32[1][i] = 0.f; sum32[i] = 0.f; }

    const u16* kg = qkv + (size_t)(b * 2048) * 3072 + h * 192 + 64;
    const u16* vg = vt + (size_t)bh * 64 * 2048;

    // staging geometry: chunk j covers rows j*32 + wv*8 + (lane>>3);
    // physical granule lane&7 must hold logical granule (lane&7)^(row&7).
    const int lrow = lane >> 3;            // row within the wave's 8-row slab
    const int lgr  = (lane & 7) ^ lrow;    // pre-swizzled logical granule
    const int r0   = wv * 8 + lrow;        // chunk-0 row (chunk-1 = +32)

    const short8 ones = (short8){0x3F80, 0x3F80, 0x3F80, 0x3F80, 0x3F80, 0x3F80, 0x3F80, 0x3F80};

    // prologue: stage tile 0 into buffer 0
#pragma unroll
    for (int j = 0; j < 2; j++) {
        int row = j * 32 + r0;
        gld_lds16(kg + (size_t)row * 3072 + lgr * 8, (char*)&Ks[0][0] + (size_t)(j * 256 + tid) * 16);
        gld_lds16(vg + (size_t)row * 2048 + lgr * 8, (char*)&Vts[0][0] + (size_t)(j * 256 + tid) * 16);
    }
    __syncthreads();

    int cur = 0;
    for (int kb = 0; kb < 2048; kb += 64) {
        // prefetch next tile into the other buffer (hidden under compute)
        if (kb + 64 < 2048) {
            int nb = cur ^ 1;
#pragma unroll
            for (int j = 0; j < 2; j++) {
                int row = j * 32 + r0;
                gld_lds16(kg + (size_t)(kb + 64 + row) * 3072 + lgr * 8,
                          (char*)&Ks[nb][0] + (size_t)(j * 256 + tid) * 16);
                gld_lds16(vg + (size_t)row * 2048 + kb + 64 + lgr * 8,
                          (char*)&Vts[nb][0] + (size_t)(j * 256 + tid) * 16);
            }
        }

#pragma unroll
        for (int kblk = 0; kblk < 2; kblk++) {
            // S^T(32 keys x 32 q) = K_blk * Q^T
            f32x16 s32;
#pragma unroll
            for (int i = 0; i < 16; i++) s32[i] = 0.f;
            __builtin_amdgcn_s_setprio(1);
#pragma unroll
            for (int ds = 0; ds < 4; ds++) {
                short8 kf = *(const short8*)(&Ks[cur][0] + (kblk * 32 + l31) * 64 + ((ds * 16 + hf * 8) ^ ex));
                s32 = __builtin_amdgcn_mfma_f32_32x32x16_bf16(kf, qr[ds], s32, 0, 0, 0);
            }
            __builtin_amdgcn_s_setprio(0);

            // P = exp2(S^T), pack pairs: pw[j]@half g = keys kblk*32+(2j&3)+8*(j>>1)+4g+{0,1}
            u32 pw[8];
#pragma unroll
            for (int j = 0; j < 8; j++)
                pw[j] = pack_bf16_trunc(__builtin_amdgcn_exp2f(s32[2 * j]),
                                        __builtin_amdgcn_exp2f(s32[2 * j + 1]));

            // two 16-key PV steps for this key block
#pragma unroll
            for (int th = 0; th < 2; th++) {
                const int t = 2 * kblk + th;
                const int J0 = 4 * th;
                u32 a0 = pw[J0],     a1 = pw[J0 + 2];
                u32 b0 = pw[J0 + 1], b1 = pw[J0 + 3];
                plswap32(a0, a1);   // -> (w0, w2)
                plswap32(b0, b1);   // -> (w1, w3)
                u32x4 wf = (u32x4){a0, b0, a1, b1};
                short8 pa = __builtin_bit_cast(short8, wf);

                sum32 = __builtin_amdgcn_mfma_f32_32x32x16_bf16(pa, ones, sum32, 0, 0, 0);
                __builtin_amdgcn_s_setprio(1);
#pragma unroll
                for (int db = 0; db < 2; db++) {
                    short8 vf = *(const short8*)(&Vts[cur][0] + (db * 32 + l31) * 64 + ((t * 16 + hf * 8) ^ ex));
                    o32[db] = __builtin_amdgcn_mfma_f32_32x32x16_bf16(pa, vf, o32[db], 0, 0, 0);
                }
                __builtin_amdgcn_s_setprio(0);
            }
        }

        __syncthreads();   // implicit vmcnt(0): prefetch complete; all reads of [cur] done
        cur ^= 1;
    }

    // epilogue: normalize and write vals2 in the no-head-transpose reshape layout.
    f32x16 inv;
#pragma unroll
    for (int r = 0; r < 16; r++) inv[r] = 1.0f / sum32[r];
#pragma unroll
    for (int db = 0; db < 2; db++) {
        int d = db * 32 + l31;
#pragma unroll
        for (int r = 0; r < 16; r++) {
            int s = s0 + wv * 32 + (r & 3) + 8 * (r >> 2) + 4 * hf;
            size_t row2 = (size_t)(b * 2048 + h * 128 + (s >> 4));
            int col2 = ((s & 15) << 6) + d;
            vals2[row2 * 1024 + col2] = f2bf(o32[db][r] * inv[r]);
        }
    }
}

// ---------- launch ----------
extern "C" void kernel_launch(void* const* d_in, const int* in_sizes, int n_in,
                              void* d_out, int out_size, void* d_ws, size_t ws_size,
                              hipStream_t stream) {
    (void)in_sizes; (void)n_in; (void)out_size; (void)ws_size;
    const float* x      = (const float*)d_in[0];   // (4,2048,1024)
    const float* w_qkv  = (const float*)d_in[1];   // (3072,1024)
    const float* b_qkv  = (const float*)d_in[2];   // (3072,)
    const float* w_o    = (const float*)d_in[3];   // (1024,1024)
    const float* b_o    = (const float*)d_in[4];   // (1024,)
    float* out = (float*)d_out;

    char* ws = (char*)d_ws;
    u16* xb   = (u16*)(ws);                          // 16 MB  x bf16 (8192x1024)
    u16* wqb  = (u16*)(ws + 16777216);               // 6 MB   w_qkv bf16 (Q rows pre-scaled)
    u16* wob  = (u16*)(ws + 23068672);               // 2 MB   w_o bf16
    u16* qkvb = (u16*)(ws + 25165824);               // 48 MB  qkv bf16 (Q,K sections only)
    u16* vtb  = (u16*)(ws + 75497472);               // 16 MB  V^T bf16 (64bh x 64d x 2048s)
    u16* v2b  = (u16*)(ws + 92274688);               // 16 MB  vals2 bf16 (8192x1024)
    // scaled b_qkv lives in the v2b region: consumed by gemm_qkv, which
    // completes (same stream) before flash_attn overwrites v2b.
    float* bsc = (float*)(ws + 92274688);

    prep_inputs<<<6156, 256, 0, stream>>>(x, w_qkv, b_qkv, w_o, xb, wqb, wob, bsc);

    // qkv = x * w_qkv^T + b_qkv ; V section written transposed to vtb
    gemm_qkv<<<dim3(24, 64), 256, 0, stream>>>(xb, wqb, bsc, qkvb, vtb);

    // attention -> vals2 (bf16, quirky reshape layout)
    flash_attn<<<dim3(16, 64), 256, 0, stream>>>(qkvb, vtb, v2b);

    // out = vals2 * w_o^T + b_o   (M=8192, N=1024, K=1024), fp32 out
    gemm_out<<<dim3(16, 64), 256, 0, stream>>>(v2b, wob, b_o, out);
}

// Round 5
// 280.030 us; speedup vs baseline: 1.0136x; 1.0136x over previous
//
#include <hip/hip_runtime.h>
#include <stdint.h>
#include <stddef.h>

#define DEVINL __device__ __forceinline__

typedef unsigned short u16;
typedef unsigned int u32;
typedef __attribute__((ext_vector_type(8))) short short8;
typedef __attribute__((ext_vector_type(4))) float f32x4;
typedef __attribute__((ext_vector_type(16))) float f32x16;
typedef __attribute__((ext_vector_type(4))) u32 u32x4;
typedef __attribute__((ext_vector_type(2))) u32 u32x2;

// log2(e)/8 : folded into W_q / b_q so flash's exp2 needs no multiply
#define QSCALE 0.18033688011112042f

// ---------- helpers ----------
DEVINL u16 f2bf(float f) {
    u32 u = __builtin_bit_cast(u32, f);
    u32 r = (u + 0x7fffu + ((u >> 16) & 1u)) >> 16;   // RNE
    return (u16)r;
}

DEVINL void gld_lds16(const void* g, void* l) {
    __builtin_amdgcn_global_load_lds(
        (__attribute__((address_space(1))) u32*)(uintptr_t)g,
        (__attribute__((address_space(3))) u32*)l, 16, 0, 0);
}

// pack two fp32 -> bf16x2 by truncation (bias cancels: denominator sums the same bf16 P)
DEVINL u32 pack_bf16_trunc(float lo, float hi) {
    return __builtin_amdgcn_perm(__builtin_bit_cast(u32, hi),
                                 __builtin_bit_cast(u32, lo), 0x07060302u);
}

// cross-lane half swap (gfx950), both outputs used:
// a' = {a[0:31], b[0:31]}, b' = {a[32:63], b[32:63]}
DEVINL void plswap32(u32 &a, u32 &b) {
#if __has_builtin(__builtin_amdgcn_permlane32_swap)
    u32x2 r = __builtin_amdgcn_permlane32_swap(a, b, false, false);
    a = r[0]; b = r[1];
#else
    asm("v_permlane32_swap_b32 %0, %1" : "+v"(a), "+v"(b));
#endif
}

// ---------- fused input prep: casts + scale folding, one launch ----------
// blocks [0,4096): x -> xb ; [4096,5632): w_qkv -> wqb (Q rows scaled)
// [5632,6144): w_o -> wob ; [6144,6156): b_qkv scale -> bsc
__global__ void prep_inputs(const float* __restrict__ x, const float* __restrict__ wqkv,
                            const float* __restrict__ bqkv, const float* __restrict__ wo,
                            u16* __restrict__ xb, u16* __restrict__ wqb,
                            u16* __restrict__ wob, float* __restrict__ bsc) {
    int blk = blockIdx.x;
    if (blk < 6144) {
        const float* src; u16* dst; int base; bool qscale = false;
        if (blk < 4096)      { src = x;    dst = xb;  base = blk; }
        else if (blk < 5632) { src = wqkv; dst = wqb; base = blk - 4096; qscale = true; }
        else                 { src = wo;   dst = wob; base = blk - 5632; }
        int i = (base * 256 + threadIdx.x) * 8;
        float sc = 1.0f;
        if (qscale) { int row = i >> 10; if ((row % 192) < 64) sc = QSCALE; }
        float4 a = *(const float4*)(src + i);
        float4 c = *(const float4*)(src + i + 4);
        union { u16 s[8]; u32x4 v; } t;
        t.s[0] = f2bf(a.x * sc); t.s[1] = f2bf(a.y * sc); t.s[2] = f2bf(a.z * sc); t.s[3] = f2bf(a.w * sc);
        t.s[4] = f2bf(c.x * sc); t.s[5] = f2bf(c.y * sc); t.s[6] = f2bf(c.z * sc); t.s[7] = f2bf(c.w * sc);
        *(u32x4*)(dst + i) = t.v;
    } else {
        int i = (blk - 6144) * 256 + threadIdx.x;   // 0..3071
        float sc = ((i % 192) < 64) ? QSCALE : 1.0f;
        bsc[i] = bqkv[i] * sc;
    }
}

// ---------- QKV GEMM  qkv[M,3072] = x[M,K] * w_qkv[3072,K]^T + b ----------
// V-section columns (col%192 in [128,192)) are written TRANSPOSED straight to
// vt[bh][d][s] (one 8B store per lane); Q/K go to qkvb. 16-col groups never
// straddle section boundaries, so the branch is wave-uniform.
__global__ void gemm_qkv(const u16* __restrict__ A, const u16* __restrict__ Bm,
                         const float* __restrict__ bias, u16* __restrict__ qkvb,
                         u16* __restrict__ vtb) {
    const int K = 1024, N = 3072;
    __shared__ u16 As[128 * 32];
    __shared__ u16 Bs[128 * 32];
    const int tid = threadIdx.x;
    const int lane = tid & 63;
    const int wv = tid >> 6, wr = wv >> 1, wc = wv & 1;
    const int l15 = lane & 15, quad = lane >> 4;
    const int m0 = blockIdx.y * 128, n0 = blockIdx.x * 128;

    f32x4 acc[4][4];
#pragma unroll
    for (int i = 0; i < 4; i++)
#pragma unroll
        for (int j = 0; j < 4; j++) acc[i][j] = (f32x4){0.f, 0.f, 0.f, 0.f};

    const u16* Ab = A + (size_t)m0 * K;
    const u16* Bb = Bm + (size_t)n0 * K;
    const int srow = tid >> 2;
    const int sc8 = (tid & 3) * 8;

    for (int k0 = 0; k0 < K; k0 += 32) {
#pragma unroll
        for (int i = 0; i < 2; i++) {
            int row = i * 64 + srow;
            gld_lds16(Ab + (size_t)row * K + k0 + sc8, (char*)As + (size_t)(i * 256 + tid) * 16);
            gld_lds16(Bb + (size_t)row * K + k0 + sc8, (char*)Bs + (size_t)(i * 256 + tid) * 16);
        }
        __syncthreads();
        short8 af[4], bf8[4];
#pragma unroll
        for (int mi = 0; mi < 4; mi++)
            af[mi] = *(const short8*)(As + (wr * 64 + mi * 16 + l15) * 32 + quad * 8);
#pragma unroll
        for (int ni = 0; ni < 4; ni++)
            bf8[ni] = *(const short8*)(Bs + (wc * 64 + ni * 16 + l15) * 32 + quad * 8);
#pragma unroll
        for (int mi = 0; mi < 4; mi++)
#pragma unroll
            for (int ni = 0; ni < 4; ni++)
                acc[mi][ni] = __builtin_amdgcn_mfma_f32_16x16x32_bf16(af[mi], bf8[ni], acc[mi][ni], 0, 0, 0);
        __syncthreads();
    }

#pragma unroll
    for (int mi = 0; mi < 4; mi++) {
        int row_b = m0 + wr * 64 + mi * 16 + quad * 4;
#pragma unroll
        for (int ni = 0; ni < 4; ni++) {
            int c0 = n0 + wc * 64 + ni * 16;          // group base (16-aligned)
            int sec0 = c0 % 192;                       // section offset, wave-uniform
            float bv = bias[c0 + l15];
            float v0 = acc[mi][ni][0] + bv;
            float v1 = acc[mi][ni][1] + bv;
            float v2 = acc[mi][ni][2] + bv;
            float v3 = acc[mi][ni][3] + bv;
            if (sec0 >= 128) {
                // V element: transpose-store to vt[bh][d][s], 4 consecutive s
                int hh = c0 / 192;
                int b = row_b >> 11;
                int s = row_b & 2047;
                int d = sec0 - 128 + l15;
                u32 lo = (u32)f2bf(v0) | ((u32)f2bf(v1) << 16);
                u32 hi = (u32)f2bf(v2) | ((u32)f2bf(v3) << 16);
                *(u32x2*)(vtb + ((size_t)((b * 16 + hh) * 64 + d)) * 2048 + s) = (u32x2){lo, hi};
            } else {
                int col = c0 + l15;
                qkvb[(size_t)(row_b + 0) * N + col] = f2bf(v0);
                qkvb[(size_t)(row_b + 1) * N + col] = f2bf(v1);
                qkvb[(size_t)(row_b + 2) * N + col] = f2bf(v2);
                qkvb[(size_t)(row_b + 3) * N + col] = f2bf(v3);
            }
        }
    }
}

// ---------- out GEMM  out[M,1024] = vals2[M,K] * w_o[1024,K]^T + b_o ----------
// 128x64 tiles -> 1024 blocks (4/CU) for occupancy; fp32 output.
__global__ void gemm_out(const u16* __restrict__ A, const u16* __restrict__ Bm,
                         const float* __restrict__ bias, float* __restrict__ C) {
    const int K = 1024, N = 1024;
    __shared__ u16 As[128 * 32];   // 8 KB
    __shared__ u16 Bs[64 * 32];    // 4 KB
    const int tid = threadIdx.x;
    const int lane = tid & 63;
    const int wv = tid >> 6, wr = wv >> 1, wc = wv & 1;
    const int l15 = lane & 15, quad = lane >> 4;
    const int m0 = blockIdx.y * 128, n0 = blockIdx.x * 64;

    f32x4 acc[4][2];
#pragma unroll
    for (int i = 0; i < 4; i++)
#pragma unroll
        for (int j = 0; j < 2; j++) acc[i][j] = (f32x4){0.f, 0.f, 0.f, 0.f};

    const u16* Ab = A + (size_t)m0 * K;
    const u16* Bb = Bm + (size_t)n0 * K;
    const int srow = tid >> 2;
    const int sc8 = (tid & 3) * 8;

    for (int k0 = 0; k0 < K; k0 += 32) {
#pragma unroll
        for (int i = 0; i < 2; i++)
            gld_lds16(Ab + (size_t)(i * 64 + srow) * K + k0 + sc8, (char*)As + (size_t)(i * 256 + tid) * 16);
        gld_lds16(Bb + (size_t)srow * K + k0 + sc8, (char*)Bs + (size_t)tid * 16);
        __syncthreads();
        short8 af[4], bf8[2];
#pragma unroll
        for (int mi = 0; mi < 4; mi++)
            af[mi] = *(const short8*)(As + (wr * 64 + mi * 16 + l15) * 32 + quad * 8);
#pragma unroll
        for (int ni = 0; ni < 2; ni++)
            bf8[ni] = *(const short8*)(Bs + (wc * 32 + ni * 16 + l15) * 32 + quad * 8);
#pragma unroll
        for (int mi = 0; mi < 4; mi++)
#pragma unroll
            for (int ni = 0; ni < 2; ni++)
                acc[mi][ni] = __builtin_amdgcn_mfma_f32_16x16x32_bf16(af[mi], bf8[ni], acc[mi][ni], 0, 0, 0);
        __syncthreads();
    }

#pragma unroll
    for (int mi = 0; mi < 4; mi++) {
        int row_b = m0 + wr * 64 + mi * 16 + quad * 4;
#pragma unroll
        for (int ni = 0; ni < 2; ni++) {
            int col = n0 + wc * 32 + ni * 16 + l15;
            float bv = bias[col];
#pragma unroll
            for (int r = 0; r < 4; r++)
                C[(size_t)(row_b + r) * N + col] = acc[mi][ni][r] + bv;
        }
    }
}

// ---------- flash attention (round-7: 32x32 MFMA + row-bit4-aware swizzle) ----------
// Same structure as round-6 (32x32x16 MFMA, 2-swap in-register P redistribution,
// double-buffered K/Vt via global_load_lds, one barrier/iter).  Swizzle upgraded:
//   phys_granule(row, lg) = lg ^ (row&7) ^ (((row>>4)&1)<<1)
// Round-6's  lg ^ (row&7)  left lanes 16-apart (sharing lane&7 and half) on the
// SAME granule while reading rows 16 apart (same banks, distinct addresses) ->
// measured 2^23 conflict-cycles (+4 cyc per b128 read).  Folding row-bit-4 into
// granule-bit-1 makes every {l, l+8, l+16, l+24} lane group hit 4 distinct
// granules; residual aliasing is <=2-way (free, m136).  Staging keeps the
// linear-dest + pre-swizzled-source rule with the same extra XOR term.
__launch_bounds__(256, 4)
__global__ void flash_attn(const u16* __restrict__ qkv, const u16* __restrict__ vt,
                           u16* __restrict__ vals2) {
    __shared__ u16 Ks[2][64 * 64];   // 2 x 8 KB: 64 keys x 64 d (swizzled)
    __shared__ u16 Vts[2][64 * 64];  // 2 x 8 KB: 64 d x 64 keys (swizzled)

    const int tid = threadIdx.x;
    const int lane = tid & 63, wv = tid >> 6;
    const int l31 = lane & 31, hf = lane >> 5;
    // read-side XOR (u16 units): row = (kblk|db)*32 + l31 -> row&7 = lane&7,
    // (row>>4)&1 = l31>>4.  XOR value = ((lane&7) ^ ((l31>>4)<<1)) * 8
    const int exr = (((lane & 7) ^ ((l31 >> 4) << 1))) * 8;
    const int s0 = blockIdx.x * 128;
    const int bh = blockIdx.y, b = bh >> 4, h = bh & 15;

    // Q fragments in registers: qr[ds] = Q[q = own row][d = ds*16 + hf*8 .. +8]
    // (q rows pre-scaled by log2e/8 at cast time)
    short8 qr[4];
    {
        const u16* qbase = qkv + (size_t)(b * 2048 + s0 + wv * 32 + l31) * 3072 + h * 192 + hf * 8;
#pragma unroll
        for (int ds = 0; ds < 4; ds++)
            qr[ds] = *(const short8*)(qbase + ds * 16);
    }

    f32x16 o32[2];      // [db]: col d = db*32+l31, row q = (reg&3)+8*(reg>>2)+4*hf
    f32x16 sum32;       // denominator, same q mapping, col-replicated
#pragma unroll
    for (int i = 0; i < 16; i++) { o32[0][i] = 0.f; o32[1][i] = 0.f; sum32[i] = 0.f; }

    const u16* kg = qkv + (size_t)(b * 2048) * 3072 + h * 192 + 64;
    const u16* vg = vt + (size_t)bh * 64 * 2048;

    // staging geometry: chunk j covers rows j*32 + wv*8 + (lane>>3);
    // physical granule lane&7 holds logical granule (lane&7) ^ v(row) where
    // v(row) = (row&7) ^ (((row>>4)&1)<<1) = lrow ^ (((wv>>1)&1)<<1)
    const int lrow = lane >> 3;            // row within the wave's 8-row slab
    const int lgr  = (lane & 7) ^ lrow ^ (((wv >> 1) & 1) << 1);
    const int r0   = wv * 8 + lrow;        // chunk-0 row (chunk-1 = +32)

    const short8 ones = (short8){0x3F80, 0x3F80, 0x3F80, 0x3F80, 0x3F80, 0x3F80, 0x3F80, 0x3F80};

    // prologue: stage tile 0 into buffer 0
#pragma unroll
    for (int j = 0; j < 2; j++) {
        int row = j * 32 + r0;
        gld_lds16(kg + (size_t)row * 3072 + lgr * 8, (char*)&Ks[0][0] + (size_t)(j * 256 + tid) * 16);
        gld_lds16(vg + (size_t)row * 2048 + lgr * 8, (char*)&Vts[0][0] + (size_t)(j * 256 + tid) * 16);
    }
    __syncthreads();

    int cur = 0;
    for (int kb = 0; kb < 2048; kb += 64) {
        // prefetch next tile into the other buffer (hidden under compute)
        if (kb + 64 < 2048) {
            int nb = cur ^ 1;
#pragma unroll
            for (int j = 0; j < 2; j++) {
                int row = j * 32 + r0;
                gld_lds16(kg + (size_t)(kb + 64 + row) * 3072 + lgr * 8,
                          (char*)&Ks[nb][0] + (size_t)(j * 256 + tid) * 16);
                gld_lds16(vg + (size_t)row * 2048 + kb + 64 + lgr * 8,
                          (char*)&Vts[nb][0] + (size_t)(j * 256 + tid) * 16);
            }
        }

#pragma unroll
        for (int kblk = 0; kblk < 2; kblk++) {
            // S^T(32 keys x 32 q) = K_blk * Q^T
            f32x16 s32;
#pragma unroll
            for (int i = 0; i < 16; i++) s32[i] = 0.f;
            __builtin_amdgcn_s_setprio(1);
#pragma unroll
            for (int ds = 0; ds < 4; ds++) {
                short8 kf = *(const short8*)(&Ks[cur][0] + (kblk * 32 + l31) * 64 + ((ds * 16 + hf * 8) ^ exr));
                s32 = __builtin_amdgcn_mfma_f32_32x32x16_bf16(kf, qr[ds], s32, 0, 0, 0);
            }
            __builtin_amdgcn_s_setprio(0);

            // P = exp2(S^T), pack pairs: pw[j]@half g = keys kblk*32+(2j&3)+8*(j>>1)+4g+{0,1}
            u32 pw[8];
#pragma unroll
            for (int j = 0; j < 8; j++)
                pw[j] = pack_bf16_trunc(__builtin_amdgcn_exp2f(s32[2 * j]),
                                        __builtin_amdgcn_exp2f(s32[2 * j + 1]));

            // two 16-key PV steps for this key block
#pragma unroll
            for (int th = 0; th < 2; th++) {
                const int t = 2 * kblk + th;
                const int J0 = 4 * th;
                u32 a0 = pw[J0],     a1 = pw[J0 + 2];
                u32 b0 = pw[J0 + 1], b1 = pw[J0 + 3];
                plswap32(a0, a1);   // -> (w0, w2)
                plswap32(b0, b1);   // -> (w1, w3)
                u32x4 wf = (u32x4){a0, b0, a1, b1};
                short8 pa = __builtin_bit_cast(short8, wf);

                sum32 = __builtin_amdgcn_mfma_f32_32x32x16_bf16(pa, ones, sum32, 0, 0, 0);
                __builtin_amdgcn_s_setprio(1);
#pragma unroll
                for (int db = 0; db < 2; db++) {
                    short8 vf = *(const short8*)(&Vts[cur][0] + (db * 32 + l31) * 64 + ((t * 16 + hf * 8) ^ exr));
                    o32[db] = __builtin_amdgcn_mfma_f32_32x32x16_bf16(pa, vf, o32[db], 0, 0, 0);
                }
                __builtin_amdgcn_s_setprio(0);
            }
        }

        __syncthreads();   // implicit vmcnt(0): prefetch complete; all reads of [cur] done
        cur ^= 1;
    }

    // epilogue: normalize and write vals2 in the no-head-transpose reshape layout.
    f32x16 inv;
#pragma unroll
    for (int r = 0; r < 16; r++) inv[r] = 1.0f / sum32[r];
#pragma unroll
    for (int db = 0; db < 2; db++) {
        int d = db * 32 + l31;
#pragma unroll
        for (int r = 0; r < 16; r++) {
            int s = s0 + wv * 32 + (r & 3) + 8 * (r >> 2) + 4 * hf;
            size_t row2 = (size_t)(b * 2048 + h * 128 + (s >> 4));
            int col2 = ((s & 15) << 6) + d;
            vals2[row2 * 1024 + col2] = f2bf(o32[db][r] * inv[r]);
        }
    }
}

// ---------- launch ----------
extern "C" void kernel_launch(void* const* d_in, const int* in_sizes, int n_in,
                              void* d_out, int out_size, void* d_ws, size_t ws_size,
                              hipStream_t stream) {
    (void)in_sizes; (void)n_in; (void)out_size; (void)ws_size;
    const float* x      = (const float*)d_in[0];   // (4,2048,1024)
    const float* w_qkv  = (const float*)d_in[1];   // (3072,1024)
    const float* b_qkv  = (const float*)d_in[2];   // (3072,)
    const float* w_o    = (const float*)d_in[3];   // (1024,1024)
    const float* b_o    = (const float*)d_in[4];   // (1024,)
    float* out = (float*)d_out;

    char* ws = (char*)d_ws;
    u16* xb   = (u16*)(ws);                          // 16 MB  x bf16 (8192x1024)
    u16* wqb  = (u16*)(ws + 16777216);               // 6 MB   w_qkv bf16 (Q rows pre-scaled)
    u16* wob  = (u16*)(ws + 23068672);               // 2 MB   w_o bf16
    u16* qkvb = (u16*)(ws + 25165824);               // 48 MB  qkv bf16 (Q,K sections only)
    u16* vtb  = (u16*)(ws + 75497472);               // 16 MB  V^T bf16 (64bh x 64d x 2048s)
    u16* v2b  = (u16*)(ws + 92274688);               // 16 MB  vals2 bf16 (8192x1024)
    // scaled b_qkv lives in the v2b region: consumed by gemm_qkv, which
    // completes (same stream) before flash_attn overwrites v2b.
    float* bsc = (float*)(ws + 92274688);

    prep_inputs<<<6156, 256, 0, stream>>>(x, w_qkv, b_qkv, w_o, xb, wqb, wob, bsc);

    // qkv = x * w_qkv^T + b_qkv ; V section written transposed to vtb
    gemm_qkv<<<dim3(24, 64), 256, 0, stream>>>(xb, wqb, bsc, qkvb, vtb);

    // attention -> vals2 (bf16, quirky reshape layout)
    flash_attn<<<dim3(16, 64), 256, 0, stream>>>(qkvb, vtb, v2b);

    // out = vals2 * w_o^T + b_o   (M=8192, N=1024, K=1024), fp32 out
    gemm_out<<<dim3(16, 64), 256, 0, stream>>>(v2b, wob, b_o, out);
}

// Round 6
// 270.482 us; speedup vs baseline: 1.0494x; 1.0353x over previous
//
#include <hip/hip_runtime.h>
#include <stdint.h>
#include <stddef.h>

#define DEVINL __device__ __forceinline__

typedef unsigned short u16;
typedef unsigned int u32;
typedef __attribute__((ext_vector_type(8))) short short8;
typedef __attribute__((ext_vector_type(4))) float f32x4;
typedef __attribute__((ext_vector_type(4))) u32 u32x4;
typedef __attribute__((ext_vector_type(2))) u32 u32x2;

// log2(e)/8 : folded into W_q / b_q so flash's exp2 needs no multiply
#define QSCALE 0.18033688011112042f

// ---------- helpers ----------
DEVINL u16 f2bf(float f) {
    u32 u = __builtin_bit_cast(u32, f);
    u32 r = (u + 0x7fffu + ((u >> 16) & 1u)) >> 16;   // RNE
    return (u16)r;
}

DEVINL void gld_lds16(const void* g, void* l) {
    __builtin_amdgcn_global_load_lds(
        (__attribute__((address_space(1))) u32*)(uintptr_t)g,
        (__attribute__((address_space(3))) u32*)l, 16, 0, 0);
}

// pack two fp32 -> bf16x2 by truncation (bias cancels: denominator sums the same bf16 P)
DEVINL u32 pack_bf16_trunc(float lo, float hi) {
    return __builtin_amdgcn_perm(__builtin_bit_cast(u32, hi),
                                 __builtin_bit_cast(u32, lo), 0x07060302u);
}

// cross-lane half swaps (gfx950): both outputs are used.
DEVINL void plswap32(u32 &a, u32 &b) {
#if __has_builtin(__builtin_amdgcn_permlane32_swap)
    u32x2 r = __builtin_amdgcn_permlane32_swap(a, b, false, false);
    a = r[0]; b = r[1];
#else
    asm("v_permlane32_swap_b32 %0, %1" : "+v"(a), "+v"(b));
#endif
}
DEVINL void plswap16(u32 &a, u32 &b) {
#if __has_builtin(__builtin_amdgcn_permlane16_swap)
    u32x2 r = __builtin_amdgcn_permlane16_swap(a, b, false, false);
    a = r[0]; b = r[1];
#else
    asm("v_permlane16_swap_b32 %0, %1" : "+v"(a), "+v"(b));
#endif
}

// ---------- fused input prep: casts + scale folding, one launch ----------
// blocks [0,4096): x -> xb ; [4096,5632): w_qkv -> wqb (Q rows scaled)
// [5632,6144): w_o -> wob ; [6144,6156): b_qkv scale -> bsc
__global__ void prep_inputs(const float* __restrict__ x, const float* __restrict__ wqkv,
                            const float* __restrict__ bqkv, const float* __restrict__ wo,
                            u16* __restrict__ xb, u16* __restrict__ wqb,
                            u16* __restrict__ wob, float* __restrict__ bsc) {
    int blk = blockIdx.x;
    if (blk < 6144) {
        const float* src; u16* dst; int base; bool qscale = false;
        if (blk < 4096)      { src = x;    dst = xb;  base = blk; }
        else if (blk < 5632) { src = wqkv; dst = wqb; base = blk - 4096; qscale = true; }
        else                 { src = wo;   dst = wob; base = blk - 5632; }
        int i = (base * 256 + threadIdx.x) * 8;
        float sc = 1.0f;
        if (qscale) { int row = i >> 10; if ((row % 192) < 64) sc = QSCALE; }
        float4 a = *(const float4*)(src + i);
        float4 c = *(const float4*)(src + i + 4);
        union { u16 s[8]; u32x4 v; } t;
        t.s[0] = f2bf(a.x * sc); t.s[1] = f2bf(a.y * sc); t.s[2] = f2bf(a.z * sc); t.s[3] = f2bf(a.w * sc);
        t.s[4] = f2bf(c.x * sc); t.s[5] = f2bf(c.y * sc); t.s[6] = f2bf(c.z * sc); t.s[7] = f2bf(c.w * sc);
        *(u32x4*)(dst + i) = t.v;
    } else {
        int i = (blk - 6144) * 256 + threadIdx.x;   // 0..3071
        float sc = ((i % 192) < 64) ? QSCALE : 1.0f;
        bsc[i] = bqkv[i] * sc;
    }
}

// ---------- QKV GEMM  qkv[M,3072] = x[M,K] * w_qkv[3072,K]^T + b ----------
// V-section columns (col%192 in [128,192)) are written TRANSPOSED straight to
// vt[bh][d][s] (one 8B store per lane); Q/K go to qkvb. 16-col groups never
// straddle section boundaries, so the branch is wave-uniform.
__global__ void gemm_qkv(const u16* __restrict__ A, const u16* __restrict__ Bm,
                         const float* __restrict__ bias, u16* __restrict__ qkvb,
                         u16* __restrict__ vtb) {
    const int K = 1024, N = 3072;
    __shared__ u16 As[128 * 32];
    __shared__ u16 Bs[128 * 32];
    const int tid = threadIdx.x;
    const int lane = tid & 63;
    const int wv = tid >> 6, wr = wv >> 1, wc = wv & 1;
    const int l15 = lane & 15, quad = lane >> 4;
    const int m0 = blockIdx.y * 128, n0 = blockIdx.x * 128;

    f32x4 acc[4][4];
#pragma unroll
    for (int i = 0; i < 4; i++)
#pragma unroll
        for (int j = 0; j < 4; j++) acc[i][j] = (f32x4){0.f, 0.f, 0.f, 0.f};

    const u16* Ab = A + (size_t)m0 * K;
    const u16* Bb = Bm + (size_t)n0 * K;
    const int srow = tid >> 2;
    const int sc8 = (tid & 3) * 8;

    for (int k0 = 0; k0 < K; k0 += 32) {
#pragma unroll
        for (int i = 0; i < 2; i++) {
            int row = i * 64 + srow;
            gld_lds16(Ab + (size_t)row * K + k0 + sc8, (char*)As + (size_t)(i * 256 + tid) * 16);
            gld_lds16(Bb + (size_t)row * K + k0 + sc8, (char*)Bs + (size_t)(i * 256 + tid) * 16);
        }
        __syncthreads();
        short8 af[4], bf8[4];
#pragma unroll
        for (int mi = 0; mi < 4; mi++)
            af[mi] = *(const short8*)(As + (wr * 64 + mi * 16 + l15) * 32 + quad * 8);
#pragma unroll
        for (int ni = 0; ni < 4; ni++)
            bf8[ni] = *(const short8*)(Bs + (wc * 64 + ni * 16 + l15) * 32 + quad * 8);
#pragma unroll
        for (int mi = 0; mi < 4; mi++)
#pragma unroll
            for (int ni = 0; ni < 4; ni++)
                acc[mi][ni] = __builtin_amdgcn_mfma_f32_16x16x32_bf16(af[mi], bf8[ni], acc[mi][ni], 0, 0, 0);
        __syncthreads();
    }

#pragma unroll
    for (int mi = 0; mi < 4; mi++) {
        int row_b = m0 + wr * 64 + mi * 16 + quad * 4;
#pragma unroll
        for (int ni = 0; ni < 4; ni++) {
            int c0 = n0 + wc * 64 + ni * 16;          // group base (16-aligned)
            int sec0 = c0 % 192;                       // section offset, wave-uniform
            float bv = bias[c0 + l15];
            float v0 = acc[mi][ni][0] + bv;
            float v1 = acc[mi][ni][1] + bv;
            float v2 = acc[mi][ni][2] + bv;
            float v3 = acc[mi][ni][3] + bv;
            if (sec0 >= 128) {
                // V element: transpose-store to vt[bh][d][s], 4 consecutive s
                int hh = c0 / 192;
                int b = row_b >> 11;
                int s = row_b & 2047;
                int d = sec0 - 128 + l15;
                u32 lo = (u32)f2bf(v0) | ((u32)f2bf(v1) << 16);
                u32 hi = (u32)f2bf(v2) | ((u32)f2bf(v3) << 16);
                *(u32x2*)(vtb + ((size_t)((b * 16 + hh) * 64 + d)) * 2048 + s) = (u32x2){lo, hi};
            } else {
                int col = c0 + l15;
                qkvb[(size_t)(row_b + 0) * N + col] = f2bf(v0);
                qkvb[(size_t)(row_b + 1) * N + col] = f2bf(v1);
                qkvb[(size_t)(row_b + 2) * N + col] = f2bf(v2);
                qkvb[(size_t)(row_b + 3) * N + col] = f2bf(v3);
            }
        }
    }
}

// ---------- out GEMM  out[M,1024] = vals2[M,K] * w_o[1024,K]^T + b_o ----------
// 128x64 tiles -> 1024 blocks (4/CU) for occupancy; fp32 output.
__global__ void gemm_out(const u16* __restrict__ A, const u16* __restrict__ Bm,
                         const float* __restrict__ bias, float* __restrict__ C) {
    const int K = 1024, N = 1024;
    __shared__ u16 As[128 * 32];   // 8 KB
    __shared__ u16 Bs[64 * 32];    // 4 KB
    const int tid = threadIdx.x;
    const int lane = tid & 63;
    const int wv = tid >> 6, wr = wv >> 1, wc = wv & 1;
    const int l15 = lane & 15, quad = lane >> 4;
    const int m0 = blockIdx.y * 128, n0 = blockIdx.x * 64;

    f32x4 acc[4][2];
#pragma unroll
    for (int i = 0; i < 4; i++)
#pragma unroll
        for (int j = 0; j < 2; j++) acc[i][j] = (f32x4){0.f, 0.f, 0.f, 0.f};

    const u16* Ab = A + (size_t)m0 * K;
    const u16* Bb = Bm + (size_t)n0 * K;
    const int srow = tid >> 2;
    const int sc8 = (tid & 3) * 8;

    for (int k0 = 0; k0 < K; k0 += 32) {
#pragma unroll
        for (int i = 0; i < 2; i++)
            gld_lds16(Ab + (size_t)(i * 64 + srow) * K + k0 + sc8, (char*)As + (size_t)(i * 256 + tid) * 16);
        gld_lds16(Bb + (size_t)srow * K + k0 + sc8, (char*)Bs + (size_t)tid * 16);
        __syncthreads();
        short8 af[4], bf8[2];
#pragma unroll
        for (int mi = 0; mi < 4; mi++)
            af[mi] = *(const short8*)(As + (wr * 64 + mi * 16 + l15) * 32 + quad * 8);
#pragma unroll
        for (int ni = 0; ni < 2; ni++)
            bf8[ni] = *(const short8*)(Bs + (wc * 32 + ni * 16 + l15) * 32 + quad * 8);
#pragma unroll
        for (int mi = 0; mi < 4; mi++)
#pragma unroll
            for (int ni = 0; ni < 2; ni++)
                acc[mi][ni] = __builtin_amdgcn_mfma_f32_16x16x32_bf16(af[mi], bf8[ni], acc[mi][ni], 0, 0, 0);
        __syncthreads();
    }

#pragma unroll
    for (int mi = 0; mi < 4; mi++) {
        int row_b = m0 + wr * 64 + mi * 16 + quad * 4;
#pragma unroll
        for (int ni = 0; ni < 2; ni++) {
            int col = n0 + wc * 32 + ni * 16 + l15;
            float bv = bias[col];
#pragma unroll
            for (int r = 0; r < 4; r++)
                C[(size_t)(row_b + r) * N + col] = acc[mi][ni][r] + bv;
        }
    }
}

// ---------- flash attention (round-8: R3 core + XCD-aware block remap + setprio) ----------
// Compute core is the verified round-5 kernel (16x16 MFMA, in-register P via
// permlane swaps, double-buffered K/Vt via global_load_lds with linear-dest +
// pre-swizzled source, one barrier per tile; measured 82.5 us, 0 bank conflicts).
// NEW: 1-D grid with XCD-aware remap (T1).  Linear block id n is assumed
// round-robin over 8 XCDs (n%8).  We assign  bh = (n&7)*8 + ((n>>3)>>4),
// s0 = ((n>>3)&15)*128  so each XCD owns 8 whole heads (16 s-tiles each, all
// co-resident at 4 blocks/CU x 32 CU): K/V per XCD = 4 MB = one L2, fetched
// once instead of ~4x (FETCH_SIZE was 139 MB vs ~48 MB unique).
// NEW: s_setprio(1) around MFMA clusters (T5).
__launch_bounds__(256, 4)
__global__ void flash_attn(const u16* __restrict__ qkv, const u16* __restrict__ vt,
                           u16* __restrict__ vals2) {
    __shared__ u16 Ks[2][64 * 64];   // 2 x 8 KB: 64 keys x 64 d (swizzled)
    __shared__ u16 Vts[2][64 * 64];  // 2 x 8 KB: 64 d x 64 keys (swizzled)

    const int tid = threadIdx.x;
    const int lane = tid & 63, wv = tid >> 6;
    const int l15 = lane & 15, quad = lane >> 4;
    const int e7 = (l15 & 7) * 8;          // u16-unit XOR for swizzled reads
    // XCD-aware decode of the 1-D block id
    const int id = blockIdx.x;
    const int m = id >> 3;
    const int bh = ((id & 7) << 3) + (m >> 4);
    const int s0 = (m & 15) << 7;
    const int b = bh >> 4, h = bh & 15;

    // Q fragments in registers (q rows pre-scaled by log2e/8 at cast time)
    short8 qf[2][2];
    const u16* qbase = qkv + (size_t)(b * 2048 + s0 + wv * 32) * 3072 + h * 192;
#pragma unroll
    for (int qi = 0; qi < 2; qi++)
#pragma unroll
        for (int ks = 0; ks < 2; ks++)
            qf[qi][ks] = *(const short8*)(qbase + (size_t)(qi * 16 + l15) * 3072 + ks * 32 + quad * 8);

    f32x4 o_acc[2][4];
    f32x4 sum_acc[2];
#pragma unroll
    for (int qi = 0; qi < 2; qi++) {
        sum_acc[qi] = (f32x4){0.f, 0.f, 0.f, 0.f};
#pragma unroll
        for (int nd = 0; nd < 4; nd++) o_acc[qi][nd] = (f32x4){0.f, 0.f, 0.f, 0.f};
    }

    const u16* kg = qkv + (size_t)(b * 2048) * 3072 + h * 192 + 64;
    const u16* vg = vt + (size_t)bh * 64 * 2048;

    // staging geometry: chunk j covers rows j*32 + wv*8 + (lane>>3);
    // physical granule lane&7 must hold logical granule (lane&7)^(row&7).
    const int lrow = lane >> 3;            // row within the wave's 8-row slab
    const int lgr  = (lane & 7) ^ lrow;    // pre-swizzled logical granule
    const int r0   = wv * 8 + lrow;        // chunk-0 row (chunk-1 = +32)

    const short8 ones = (short8){0x3F80, 0x3F80, 0x3F80, 0x3F80, 0x3F80, 0x3F80, 0x3F80, 0x3F80};

    // prologue: stage tile 0 into buffer 0
#pragma unroll
    for (int j = 0; j < 2; j++) {
        int row = j * 32 + r0;
        gld_lds16(kg + (size_t)row * 3072 + lgr * 8, (char*)&Ks[0][0] + (size_t)(j * 256 + tid) * 16);
        gld_lds16(vg + (size_t)row * 2048 + lgr * 8, (char*)&Vts[0][0] + (size_t)(j * 256 + tid) * 16);
    }
    __syncthreads();

    int cur = 0;
    for (int kb = 0; kb < 2048; kb += 64) {
        // prefetch next tile into the other buffer (hidden under compute)
        if (kb + 64 < 2048) {
            int nb = cur ^ 1;
#pragma unroll
            for (int j = 0; j < 2; j++) {
                int row = j * 32 + r0;
                gld_lds16(kg + (size_t)(kb + 64 + row) * 3072 + lgr * 8,
                          (char*)&Ks[nb][0] + (size_t)(j * 256 + tid) * 16);
                gld_lds16(vg + (size_t)row * 2048 + kb + 64 + lgr * 8,
                          (char*)&Vts[nb][0] + (size_t)(j * 256 + tid) * 16);
            }
        }

        // S^T = K * Q^T : s_acc[ki][qi] -> key = ki*16+quad*4+r, q = qi*16+l15
        f32x4 s_acc[4][2];
#pragma unroll
        for (int ki = 0; ki < 4; ki++)
#pragma unroll
            for (int qi = 0; qi < 2; qi++) s_acc[ki][qi] = (f32x4){0.f, 0.f, 0.f, 0.f};
        __builtin_amdgcn_s_setprio(1);
#pragma unroll
        for (int ki = 0; ki < 4; ki++) {
#pragma unroll
            for (int ks = 0; ks < 2; ks++) {
                short8 kf = *(const short8*)(&Ks[cur][0] + (ki * 16 + l15) * 64 + ((ks * 32 + quad * 8) ^ e7));
#pragma unroll
                for (int qi = 0; qi < 2; qi++)
                    s_acc[ki][qi] = __builtin_amdgcn_mfma_f32_16x16x32_bf16(kf, qf[qi][ks], s_acc[ki][qi], 0, 0, 0);
            }
        }
        __builtin_amdgcn_s_setprio(0);

        // P = exp2(S^T) -> pack bf16 pairs -> permlane swaps build PV A-frags
        // in-register (no LDS round-trip).
        short8 ap[2][2];   // [qi][c]: P[q=l15][key=c*32+quad*8+0..7]
#pragma unroll
        for (int c = 0; c < 2; c++)
#pragma unroll
            for (int qi = 0; qi < 2; qi++) {
                u32 w0 = pack_bf16_trunc(__builtin_amdgcn_exp2f(s_acc[2 * c][qi][0]),
                                         __builtin_amdgcn_exp2f(s_acc[2 * c][qi][1]));
                u32 w1 = pack_bf16_trunc(__builtin_amdgcn_exp2f(s_acc[2 * c][qi][2]),
                                         __builtin_amdgcn_exp2f(s_acc[2 * c][qi][3]));
                u32 w2 = pack_bf16_trunc(__builtin_amdgcn_exp2f(s_acc[2 * c + 1][qi][0]),
                                         __builtin_amdgcn_exp2f(s_acc[2 * c + 1][qi][1]));
                u32 w3 = pack_bf16_trunc(__builtin_amdgcn_exp2f(s_acc[2 * c + 1][qi][2]),
                                         __builtin_amdgcn_exp2f(s_acc[2 * c + 1][qi][3]));
                plswap32(w0, w2);
                plswap32(w1, w3);
                plswap16(w0, w2);
                plswap16(w1, w3);
                u32x4 wf = (u32x4){w0, w1, w2, w3};
                ap[qi][c] = __builtin_bit_cast(short8, wf);
            }

        // PV over 2 chunks of 32 keys; denominator via ones-column MFMA
#pragma unroll
        for (int c = 0; c < 2; c++) {
#pragma unroll
            for (int qi = 0; qi < 2; qi++)
                sum_acc[qi] = __builtin_amdgcn_mfma_f32_16x16x32_bf16(ap[qi][c], ones, sum_acc[qi], 0, 0, 0);
            __builtin_amdgcn_s_setprio(1);
#pragma unroll
            for (int nd = 0; nd < 4; nd++) {
                short8 bv = *(const short8*)(&Vts[cur][0] + (nd * 16 + l15) * 64 + ((c * 32 + quad * 8) ^ e7));
#pragma unroll
                for (int qi = 0; qi < 2; qi++)
                    o_acc[qi][nd] = __builtin_amdgcn_mfma_f32_16x16x32_bf16(ap[qi][c], bv, o_acc[qi][nd], 0, 0, 0);
            }
            __builtin_amdgcn_s_setprio(0);
        }

        __syncthreads();   // implicit vmcnt(0): prefetch complete; all reads of [cur] done
        cur ^= 1;
    }

    // epilogue: normalize (sum is broadcast across l15 by the ones-MFMA) and
    // write vals2 in the no-head-transpose reshape layout.
#pragma unroll
    for (int qi = 0; qi < 2; qi++) {
        f32x4 inv;
#pragma unroll
        for (int r = 0; r < 4; r++) inv[r] = 1.0f / sum_acc[qi][r];
#pragma unroll
        for (int nd = 0; nd < 4; nd++) {
            int d = nd * 16 + l15;
#pragma unroll
            for (int r = 0; r < 4; r++) {
                int s = s0 + wv * 32 + qi * 16 + quad * 4 + r;
                size_t row2 = (size_t)(b * 2048 + h * 128 + (s >> 4));
                int col2 = ((s & 15) << 6) + d;
                vals2[row2 * 1024 + col2] = f2bf(o_acc[qi][nd][r] * inv[r]);
            }
        }
    }
}

// ---------- launch ----------
extern "C" void kernel_launch(void* const* d_in, const int* in_sizes, int n_in,
                              void* d_out, int out_size, void* d_ws, size_t ws_size,
                              hipStream_t stream) {
    (void)in_sizes; (void)n_in; (void)out_size; (void)ws_size;
    const float* x      = (const float*)d_in[0];   // (4,2048,1024)
    const float* w_qkv  = (const float*)d_in[1];   // (3072,1024)
    const float* b_qkv  = (const float*)d_in[2];   // (3072,)
    const float* w_o    = (const float*)d_in[3];   // (1024,1024)
    const float* b_o    = (const float*)d_in[4];   // (1024,)
    float* out = (float*)d_out;

    char* ws = (char*)d_ws;
    u16* xb   = (u16*)(ws);                          // 16 MB  x bf16 (8192x1024)
    u16* wqb  = (u16*)(ws + 16777216);               // 6 MB   w_qkv bf16 (Q rows pre-scaled)
    u16* wob  = (u16*)(ws + 23068672);               // 2 MB   w_o bf16
    u16* qkvb = (u16*)(ws + 25165824);               // 48 MB  qkv bf16 (Q,K sections only)
    u16* vtb  = (u16*)(ws + 75497472);               // 16 MB  V^T bf16 (64bh x 64d x 2048s)
    u16* v2b  = (u16*)(ws + 92274688);               // 16 MB  vals2 bf16 (8192x1024)
    // scaled b_qkv lives in the v2b region: consumed by gemm_qkv, which
    // completes (same stream) before flash_attn overwrites v2b.
    float* bsc = (float*)(ws + 92274688);

    prep_inputs<<<6156, 256, 0, stream>>>(x, w_qkv, b_qkv, w_o, xb, wqb, wob, bsc);

    // qkv = x * w_qkv^T + b_qkv ; V section written transposed to vtb
    gemm_qkv<<<dim3(24, 64), 256, 0, stream>>>(xb, wqb, bsc, qkvb, vtb);

    // attention -> vals2 (bf16, quirky reshape layout); 1-D grid, XCD-aware remap
    flash_attn<<<1024, 256, 0, stream>>>(qkvb, vtb, v2b);

    // out = vals2 * w_o^T + b_o   (M=8192, N=1024, K=1024), fp32 out
    gemm_out<<<dim3(16, 64), 256, 0, stream>>>(v2b, wob, b_o, out);
}

// Round 7
// 269.514 us; speedup vs baseline: 1.0531x; 1.0036x over previous
//
#include <hip/hip_runtime.h>
#include <stdint.h>
#include <stddef.h>

#define DEVINL __device__ __forceinline__

typedef unsigned short u16;
typedef unsigned int u32;
typedef __attribute__((ext_vector_type(8))) short short8;
typedef __attribute__((ext_vector_type(4))) float f32x4;
typedef __attribute__((ext_vector_type(4))) u32 u32x4;
typedef __attribute__((ext_vector_type(2))) u32 u32x2;

// log2(e)/8 : folded into W_q / b_q so flash's exp2 needs no multiply
#define QSCALE 0.18033688011112042f

// ---------- helpers ----------
DEVINL u16 f2bf(float f) {
    u32 u = __builtin_bit_cast(u32, f);
    u32 r = (u + 0x7fffu + ((u >> 16) & 1u)) >> 16;   // RNE
    return (u16)r;
}

DEVINL void gld_lds16(const void* g, void* l) {
    __builtin_amdgcn_global_load_lds(
        (__attribute__((address_space(1))) u32*)(uintptr_t)g,
        (__attribute__((address_space(3))) u32*)l, 16, 0, 0);
}

// pack two fp32 -> bf16x2 by truncation (bias cancels: denominator sums the same bf16 P)
DEVINL u32 pack_bf16_trunc(float lo, float hi) {
    return __builtin_amdgcn_perm(__builtin_bit_cast(u32, hi),
                                 __builtin_bit_cast(u32, lo), 0x07060302u);
}

// cross-lane half swaps (gfx950): both outputs are used.
DEVINL void plswap32(u32 &a, u32 &b) {
#if __has_builtin(__builtin_amdgcn_permlane32_swap)
    u32x2 r = __builtin_amdgcn_permlane32_swap(a, b, false, false);
    a = r[0]; b = r[1];
#else
    asm("v_permlane32_swap_b32 %0, %1" : "+v"(a), "+v"(b));
#endif
}
DEVINL void plswap16(u32 &a, u32 &b) {
#if __has_builtin(__builtin_amdgcn_permlane16_swap)
    u32x2 r = __builtin_amdgcn_permlane16_swap(a, b, false, false);
    a = r[0]; b = r[1];
#else
    asm("v_permlane16_swap_b32 %0, %1" : "+v"(a), "+v"(b));
#endif
}

// ---------- fused input prep: casts + scale folding, one launch ----------
// blocks [0,4096): x -> xb ; [4096,5632): w_qkv -> wqb (Q rows scaled)
// [5632,6144): w_o -> wob ; [6144,6156): b_qkv scale -> bsc
__global__ void prep_inputs(const float* __restrict__ x, const float* __restrict__ wqkv,
                            const float* __restrict__ bqkv, const float* __restrict__ wo,
                            u16* __restrict__ xb, u16* __restrict__ wqb,
                            u16* __restrict__ wob, float* __restrict__ bsc) {
    int blk = blockIdx.x;
    if (blk < 6144) {
        const float* src; u16* dst; int base; bool qscale = false;
        if (blk < 4096)      { src = x;    dst = xb;  base = blk; }
        else if (blk < 5632) { src = wqkv; dst = wqb; base = blk - 4096; qscale = true; }
        else                 { src = wo;   dst = wob; base = blk - 5632; }
        int i = (base * 256 + threadIdx.x) * 8;
        float sc = 1.0f;
        if (qscale) { int row = i >> 10; if ((row % 192) < 64) sc = QSCALE; }
        float4 a = *(const float4*)(src + i);
        float4 c = *(const float4*)(src + i + 4);
        union { u16 s[8]; u32x4 v; } t;
        t.s[0] = f2bf(a.x * sc); t.s[1] = f2bf(a.y * sc); t.s[2] = f2bf(a.z * sc); t.s[3] = f2bf(a.w * sc);
        t.s[4] = f2bf(c.x * sc); t.s[5] = f2bf(c.y * sc); t.s[6] = f2bf(c.z * sc); t.s[7] = f2bf(c.w * sc);
        *(u32x4*)(dst + i) = t.v;
    } else {
        int i = (blk - 6144) * 256 + threadIdx.x;   // 0..3071
        float sc = ((i % 192) < 64) ? QSCALE : 1.0f;
        bsc[i] = bqkv[i] * sc;
    }
}

// ---------- QKV GEMM  qkv[M,3072] = x[M,K] * w_qkv[3072,K]^T + b ----------
// V-section columns (col%192 in [128,192)) are written TRANSPOSED straight to
// vt[bh][d][s] (one 8B store per lane); Q/K go to qkvb. 16-col groups never
// straddle section boundaries, so the branch is wave-uniform.
// 1-D grid, XCD-aware remap (T1): each XCD owns 8 consecutive m-tiles x all
// 24 n-tiles -> A panel 2 MB = L2-resident per XCD (was 16 MB thrash).
__global__ void gemm_qkv(const u16* __restrict__ A, const u16* __restrict__ Bm,
                         const float* __restrict__ bias, u16* __restrict__ qkvb,
                         u16* __restrict__ vtb) {
    const int K = 1024, N = 3072;
    __shared__ u16 As[128 * 32];
    __shared__ u16 Bs[128 * 32];
    const int tid = threadIdx.x;
    const int lane = tid & 63;
    const int wv = tid >> 6, wr = wv >> 1, wc = wv & 1;
    const int l15 = lane & 15, quad = lane >> 4;
    const int id = blockIdx.x;                 // 0..1535
    const int xcd = id & 7, rr = id >> 3;      // rr: 0..191
    const int m0 = ((xcd << 3) + rr / 24) * 128;
    const int n0 = (rr % 24) * 128;

    f32x4 acc[4][4];
#pragma unroll
    for (int i = 0; i < 4; i++)
#pragma unroll
        for (int j = 0; j < 4; j++) acc[i][j] = (f32x4){0.f, 0.f, 0.f, 0.f};

    const u16* Ab = A + (size_t)m0 * K;
    const u16* Bb = Bm + (size_t)n0 * K;
    const int srow = tid >> 2;
    const int sc8 = (tid & 3) * 8;

    for (int k0 = 0; k0 < K; k0 += 32) {
#pragma unroll
        for (int i = 0; i < 2; i++) {
            int row = i * 64 + srow;
            gld_lds16(Ab + (size_t)row * K + k0 + sc8, (char*)As + (size_t)(i * 256 + tid) * 16);
            gld_lds16(Bb + (size_t)row * K + k0 + sc8, (char*)Bs + (size_t)(i * 256 + tid) * 16);
        }
        __syncthreads();
        short8 af[4], bf8[4];
#pragma unroll
        for (int mi = 0; mi < 4; mi++)
            af[mi] = *(const short8*)(As + (wr * 64 + mi * 16 + l15) * 32 + quad * 8);
#pragma unroll
        for (int ni = 0; ni < 4; ni++)
            bf8[ni] = *(const short8*)(Bs + (wc * 64 + ni * 16 + l15) * 32 + quad * 8);
#pragma unroll
        for (int mi = 0; mi < 4; mi++)
#pragma unroll
            for (int ni = 0; ni < 4; ni++)
                acc[mi][ni] = __builtin_amdgcn_mfma_f32_16x16x32_bf16(af[mi], bf8[ni], acc[mi][ni], 0, 0, 0);
        __syncthreads();
    }

#pragma unroll
    for (int mi = 0; mi < 4; mi++) {
        int row_b = m0 + wr * 64 + mi * 16 + quad * 4;
#pragma unroll
        for (int ni = 0; ni < 4; ni++) {
            int c0 = n0 + wc * 64 + ni * 16;          // group base (16-aligned)
            int sec0 = c0 % 192;                       // section offset, wave-uniform
            float bv = bias[c0 + l15];
            float v0 = acc[mi][ni][0] + bv;
            float v1 = acc[mi][ni][1] + bv;
            float v2 = acc[mi][ni][2] + bv;
            float v3 = acc[mi][ni][3] + bv;
            if (sec0 >= 128) {
                // V element: transpose-store to vt[bh][d][s], 4 consecutive s
                int hh = c0 / 192;
                int b = row_b >> 11;
                int s = row_b & 2047;
                int d = sec0 - 128 + l15;
                u32 lo = (u32)f2bf(v0) | ((u32)f2bf(v1) << 16);
                u32 hi = (u32)f2bf(v2) | ((u32)f2bf(v3) << 16);
                *(u32x2*)(vtb + ((size_t)((b * 16 + hh) * 64 + d)) * 2048 + s) = (u32x2){lo, hi};
            } else {
                int col = c0 + l15;
                qkvb[(size_t)(row_b + 0) * N + col] = f2bf(v0);
                qkvb[(size_t)(row_b + 1) * N + col] = f2bf(v1);
                qkvb[(size_t)(row_b + 2) * N + col] = f2bf(v2);
                qkvb[(size_t)(row_b + 3) * N + col] = f2bf(v3);
            }
        }
    }
}

// ---------- out GEMM  out[M,1024] = vals2[M,K] * w_o[1024,K]^T + b_o ----------
// 128x64 tiles; 1-D grid with XCD remap: each XCD owns 8 m-tiles x 16 n-tiles
// -> A panel 2 MB + B 2 MB both L2-resident.
__global__ void gemm_out(const u16* __restrict__ A, const u16* __restrict__ Bm,
                         const float* __restrict__ bias, float* __restrict__ C) {
    const int K = 1024, N = 1024;
    __shared__ u16 As[128 * 32];   // 8 KB
    __shared__ u16 Bs[64 * 32];    // 4 KB
    const int tid = threadIdx.x;
    const int lane = tid & 63;
    const int wv = tid >> 6, wr = wv >> 1, wc = wv & 1;
    const int l15 = lane & 15, quad = lane >> 4;
    const int id = blockIdx.x;                 // 0..1023
    const int xcd = id & 7, rr = id >> 3;      // rr: 0..127
    const int m0 = ((xcd << 3) + (rr >> 4)) * 128;
    const int n0 = (rr & 15) * 64;

    f32x4 acc[4][2];
#pragma unroll
    for (int i = 0; i < 4; i++)
#pragma unroll
        for (int j = 0; j < 2; j++) acc[i][j] = (f32x4){0.f, 0.f, 0.f, 0.f};

    const u16* Ab = A + (size_t)m0 * K;
    const u16* Bb = Bm + (size_t)n0 * K;
    const int srow = tid >> 2;
    const int sc8 = (tid & 3) * 8;

    for (int k0 = 0; k0 < K; k0 += 32) {
#pragma unroll
        for (int i = 0; i < 2; i++)
            gld_lds16(Ab + (size_t)(i * 64 + srow) * K + k0 + sc8, (char*)As + (size_t)(i * 256 + tid) * 16);
        gld_lds16(Bb + (size_t)srow * K + k0 + sc8, (char*)Bs + (size_t)tid * 16);
        __syncthreads();
        short8 af[4], bf8[2];
#pragma unroll
        for (int mi = 0; mi < 4; mi++)
            af[mi] = *(const short8*)(As + (wr * 64 + mi * 16 + l15) * 32 + quad * 8);
#pragma unroll
        for (int ni = 0; ni < 2; ni++)
            bf8[ni] = *(const short8*)(Bs + (wc * 32 + ni * 16 + l15) * 32 + quad * 8);
#pragma unroll
        for (int mi = 0; mi < 4; mi++)
#pragma unroll
            for (int ni = 0; ni < 2; ni++)
                acc[mi][ni] = __builtin_amdgcn_mfma_f32_16x16x32_bf16(af[mi], bf8[ni], acc[mi][ni], 0, 0, 0);
        __syncthreads();
    }

#pragma unroll
    for (int mi = 0; mi < 4; mi++) {
        int row_b = m0 + wr * 64 + mi * 16 + quad * 4;
#pragma unroll
        for (int ni = 0; ni < 2; ni++) {
            int col = n0 + wc * 32 + ni * 16 + l15;
            float bv = bias[col];
#pragma unroll
            for (int r = 0; r < 4; r++)
                C[(size_t)(row_b + r) * N + col] = acc[mi][ni][r] + bv;
        }
    }
}

// ---------- flash attention (round-9: fragment-ordered LDS, zero read addressing) ----------
// Core math identical to round-8 (16x16 MFMA, in-register P via permlane swaps,
// double-buffered staging, one barrier/tile, XCD remap, setprio).  NEW: K and Vt
// are staged in MFMA-FRAGMENT ORDER.  LDS = frag[f][lane] (16 B per lane,
// f = 0..7), where fragment f of K is (ki=f>>1, ks=f&1): lane(l15,quad) holds
// K[row ki*16+l15][d ks*32+quad*8 ..+8]; Vt analogous with (nd,c).  Wave wv
// stages fragments f=wv and f=4+wv (its gld_lds dest is linear (j*256+tid)*16 =
// f*1024 + lane*16), with the per-lane GLOBAL source address delivering exactly
// the 16 B that lane consumes.  Compute-side ds_read_b128 address = lane*16 +
// immediate f*1024: no per-read VALU, and lane*16-linear is the same
// conflict-free pattern the staging writes already use (0 conflicts measured).
__launch_bounds__(256, 4)
__global__ void flash_attn(const u16* __restrict__ qkv, const u16* __restrict__ vt,
                           u16* __restrict__ vals2) {
    __shared__ u16 Ks[2][64 * 64];   // 2 x 8 KB: 8 fragments x 64 lanes x 16 B
    __shared__ u16 Vts[2][64 * 64];  // 2 x 8 KB: 8 fragments x 64 lanes x 16 B

    const int tid = threadIdx.x;
    const int lane = tid & 63, wv = tid >> 6;
    const int l15 = lane & 15, quad = lane >> 4;
    // XCD-aware decode of the 1-D block id
    const int id = blockIdx.x;
    const int m = id >> 3;
    const int bh = ((id & 7) << 3) + (m >> 4);
    const int s0 = (m & 15) << 7;
    const int b = bh >> 4, h = bh & 15;

    // Q fragments in registers (q rows pre-scaled by log2e/8 at cast time)
    short8 qf[2][2];
    const u16* qbase = qkv + (size_t)(b * 2048 + s0 + wv * 32) * 3072 + h * 192;
#pragma unroll
    for (int qi = 0; qi < 2; qi++)
#pragma unroll
        for (int ks = 0; ks < 2; ks++)
            qf[qi][ks] = *(const short8*)(qbase + (size_t)(qi * 16 + l15) * 3072 + ks * 32 + quad * 8);

    f32x4 o_acc[2][4];
    f32x4 sum_acc[2];
#pragma unroll
    for (int qi = 0; qi < 2; qi++) {
        sum_acc[qi] = (f32x4){0.f, 0.f, 0.f, 0.f};
#pragma unroll
        for (int nd = 0; nd < 4; nd++) o_acc[qi][nd] = (f32x4){0.f, 0.f, 0.f, 0.f};
    }

    const u16* kg = qkv + (size_t)(b * 2048) * 3072 + h * 192 + 64;
    const u16* vg = vt + (size_t)bh * 64 * 2048;

    // fragment-staging source offsets: wave wv stages f = j*4+wv (j=0,1).
    // K frag f=(ki,ks): lane reads K[ki*16+l15][ks*32+quad*8 ..+8]
    // Vt frag f=(nd,c): lane reads Vt[nd*16+l15][c*32+quad*8 ..+8]
    size_t ksrc[2], vsrc[2];
#pragma unroll
    for (int j = 0; j < 2; j++) {
        int f = j * 4 + wv, fi = f >> 1, fs = f & 1;
        ksrc[j] = (size_t)(fi * 16 + l15) * 3072 + fs * 32 + quad * 8;
        vsrc[j] = (size_t)(fi * 16 + l15) * 2048 + fs * 32 + quad * 8;
    }

    const short8 ones = (short8){0x3F80, 0x3F80, 0x3F80, 0x3F80, 0x3F80, 0x3F80, 0x3F80, 0x3F80};

    // prologue: stage tile 0 into buffer 0
#pragma unroll
    for (int j = 0; j < 2; j++) {
        gld_lds16(kg + ksrc[j], (char*)&Ks[0][0] + (size_t)(j * 256 + tid) * 16);
        gld_lds16(vg + vsrc[j], (char*)&Vts[0][0] + (size_t)(j * 256 + tid) * 16);
    }
    __syncthreads();

    int cur = 0;
    for (int kb = 0; kb < 2048; kb += 64) {
        // prefetch next tile into the other buffer (hidden under compute)
        if (kb + 64 < 2048) {
            int nb = cur ^ 1;
#pragma unroll
            for (int j = 0; j < 2; j++) {
                gld_lds16(kg + (size_t)(kb + 64) * 3072 + ksrc[j],
                          (char*)&Ks[nb][0] + (size_t)(j * 256 + tid) * 16);
                gld_lds16(vg + (kb + 64) + vsrc[j],
                          (char*)&Vts[nb][0] + (size_t)(j * 256 + tid) * 16);
            }
        }

        const char* kbase = (const char*)&Ks[cur][0] + lane * 16;
        const char* vbase = (const char*)&Vts[cur][0] + lane * 16;

        // S^T = K * Q^T : s_acc[ki][qi] -> key = ki*16+quad*4+r, q = qi*16+l15
        f32x4 s_acc[4][2];
#pragma unroll
        for (int ki = 0; ki < 4; ki++)
#pragma unroll
            for (int qi = 0; qi < 2; qi++) s_acc[ki][qi] = (f32x4){0.f, 0.f, 0.f, 0.f};
        __builtin_amdgcn_s_setprio(1);
#pragma unroll
        for (int ki = 0; ki < 4; ki++) {
#pragma unroll
            for (int ks = 0; ks < 2; ks++) {
                short8 kf = *(const short8*)(kbase + (ki * 2 + ks) * 1024);
#pragma unroll
                for (int qi = 0; qi < 2; qi++)
                    s_acc[ki][qi] = __builtin_amdgcn_mfma_f32_16x16x32_bf16(kf, qf[qi][ks], s_acc[ki][qi], 0, 0, 0);
            }
        }
        __builtin_amdgcn_s_setprio(0);

        // P = exp2(S^T) -> pack bf16 pairs -> permlane swaps build PV A-frags
        // in-register (no LDS round-trip).
        short8 ap[2][2];   // [qi][c]: P[q=l15][key=c*32+quad*8+0..7]
#pragma unroll
        for (int c = 0; c < 2; c++)
#pragma unroll
            for (int qi = 0; qi < 2; qi++) {
                u32 w0 = pack_bf16_trunc(__builtin_amdgcn_exp2f(s_acc[2 * c][qi][0]),
                                         __builtin_amdgcn_exp2f(s_acc[2 * c][qi][1]));
                u32 w1 = pack_bf16_trunc(__builtin_amdgcn_exp2f(s_acc[2 * c][qi][2]),
                                         __builtin_amdgcn_exp2f(s_acc[2 * c][qi][3]));
                u32 w2 = pack_bf16_trunc(__builtin_amdgcn_exp2f(s_acc[2 * c + 1][qi][0]),
                                         __builtin_amdgcn_exp2f(s_acc[2 * c + 1][qi][1]));
                u32 w3 = pack_bf16_trunc(__builtin_amdgcn_exp2f(s_acc[2 * c + 1][qi][2]),
                                         __builtin_amdgcn_exp2f(s_acc[2 * c + 1][qi][3]));
                plswap32(w0, w2);
                plswap32(w1, w3);
                plswap16(w0, w2);
                plswap16(w1, w3);
                u32x4 wf = (u32x4){w0, w1, w2, w3};
                ap[qi][c] = __builtin_bit_cast(short8, wf);
            }

        // PV over 2 chunks of 32 keys; denominator via ones-column MFMA
#pragma unroll
        for (int c = 0; c < 2; c++) {
#pragma unroll
            for (int qi = 0; qi < 2; qi++)
                sum_acc[qi] = __builtin_amdgcn_mfma_f32_16x16x32_bf16(ap[qi][c], ones, sum_acc[qi], 0, 0, 0);
            __builtin_amdgcn_s_setprio(1);
#pragma unroll
            for (int nd = 0; nd < 4; nd++) {
                short8 bv = *(const short8*)(vbase + (nd * 2 + c) * 1024);
#pragma unroll
                for (int qi = 0; qi < 2; qi++)
                    o_acc[qi][nd] = __builtin_amdgcn_mfma_f32_16x16x32_bf16(ap[qi][c], bv, o_acc[qi][nd], 0, 0, 0);
            }
            __builtin_amdgcn_s_setprio(0);
        }

        __syncthreads();   // implicit vmcnt(0): prefetch complete; all reads of [cur] done
        cur ^= 1;
    }

    // epilogue: normalize (sum is broadcast across l15 by the ones-MFMA) and
    // write vals2 in the no-head-transpose reshape layout.
#pragma unroll
    for (int qi = 0; qi < 2; qi++) {
        f32x4 inv;
#pragma unroll
        for (int r = 0; r < 4; r++) inv[r] = 1.0f / sum_acc[qi][r];
#pragma unroll
        for (int nd = 0; nd < 4; nd++) {
            int d = nd * 16 + l15;
#pragma unroll
            for (int r = 0; r < 4; r++) {
                int s = s0 + wv * 32 + qi * 16 + quad * 4 + r;
                size_t row2 = (size_t)(b * 2048 + h * 128 + (s >> 4));
                int col2 = ((s & 15) << 6) + d;
                vals2[row2 * 1024 + col2] = f2bf(o_acc[qi][nd][r] * inv[r]);
            }
        }
    }
}

// ---------- launch ----------
extern "C" void kernel_launch(void* const* d_in, const int* in_sizes, int n_in,
                              void* d_out, int out_size, void* d_ws, size_t ws_size,
                              hipStream_t stream) {
    (void)in_sizes; (void)n_in; (void)out_size; (void)ws_size;
    const float* x      = (const float*)d_in[0];   // (4,2048,1024)
    const float* w_qkv  = (const float*)d_in[1];   // (3072,1024)
    const float* b_qkv  = (const float*)d_in[2];   // (3072,)
    const float* w_o    = (const float*)d_in[3];   // (1024,1024)
    const float* b_o    = (const float*)d_in[4];   // (1024,)
    float* out = (float*)d_out;

    char* ws = (char*)d_ws;
    u16* xb   = (u16*)(ws);                          // 16 MB  x bf16 (8192x1024)
    u16* wqb  = (u16*)(ws + 16777216);               // 6 MB   w_qkv bf16 (Q rows pre-scaled)
    u16* wob  = (u16*)(ws + 23068672);               // 2 MB   w_o bf16
    u16* qkvb = (u16*)(ws + 25165824);               // 48 MB  qkv bf16 (Q,K sections only)
    u16* vtb  = (u16*)(ws + 75497472);               // 16 MB  V^T bf16 (64bh x 64d x 2048s)
    u16* v2b  = (u16*)(ws + 92274688);               // 16 MB  vals2 bf16 (8192x1024)
    // scaled b_qkv lives in the v2b region: consumed by gemm_qkv, which
    // completes (same stream) before flash_attn overwrites v2b.
    float* bsc = (float*)(ws + 92274688);

    prep_inputs<<<6156, 256, 0, stream>>>(x, w_qkv, b_qkv, w_o, xb, wqb, wob, bsc);

    // qkv = x * w_qkv^T + b_qkv ; V section written transposed to vtb (XCD remap)
    gemm_qkv<<<1536, 256, 0, stream>>>(xb, wqb, bsc, qkvb, vtb);

    // attention -> vals2 (bf16, quirky reshape layout); 1-D grid, XCD-aware remap
    flash_attn<<<1024, 256, 0, stream>>>(qkvb, vtb, v2b);

    // out = vals2 * w_o^T + b_o   (M=8192, N=1024, K=1024), fp32 out (XCD remap)
    gemm_out<<<1024, 256, 0, stream>>>(v2b, wob, b_o, out);
}

// Round 8
// 262.184 us; speedup vs baseline: 1.0826x; 1.0280x over previous
//
#include <hip/hip_runtime.h>
#include <stdint.h>
#include <stddef.h>

#define DEVINL __device__ __forceinline__

typedef unsigned short u16;
typedef unsigned int u32;
typedef __attribute__((ext_vector_type(8))) short short8;
typedef __attribute__((ext_vector_type(4))) float f32x4;
typedef __attribute__((ext_vector_type(4))) u32 u32x4;
typedef __attribute__((ext_vector_type(2))) u32 u32x2;

// log2(e)/8 : folded into W_q / b_q so flash's exp2 needs no multiply
#define QSCALE 0.18033688011112042f

// ---------- helpers ----------
DEVINL u16 f2bf(float f) {
    u32 u = __builtin_bit_cast(u32, f);
    u32 r = (u + 0x7fffu + ((u >> 16) & 1u)) >> 16;   // RNE
    return (u16)r;
}

DEVINL void gld_lds16(const void* g, void* l) {
    __builtin_amdgcn_global_load_lds(
        (__attribute__((address_space(1))) u32*)(uintptr_t)g,
        (__attribute__((address_space(3))) u32*)l, 16, 0, 0);
}

// pack two fp32 -> bf16x2 by truncation (bias cancels: denominator sums the same bf16 P)
DEVINL u32 pack_bf16_trunc(float lo, float hi) {
    return __builtin_amdgcn_perm(__builtin_bit_cast(u32, hi),
                                 __builtin_bit_cast(u32, lo), 0x07060302u);
}

// cross-lane half swaps (gfx950): both outputs are used.
DEVINL void plswap32(u32 &a, u32 &b) {
#if __has_builtin(__builtin_amdgcn_permlane32_swap)
    u32x2 r = __builtin_amdgcn_permlane32_swap(a, b, false, false);
    a = r[0]; b = r[1];
#else
    asm("v_permlane32_swap_b32 %0, %1" : "+v"(a), "+v"(b));
#endif
}
DEVINL void plswap16(u32 &a, u32 &b) {
#if __has_builtin(__builtin_amdgcn_permlane16_swap)
    u32x2 r = __builtin_amdgcn_permlane16_swap(a, b, false, false);
    a = r[0]; b = r[1];
#else
    asm("v_permlane16_swap_b32 %0, %1" : "+v"(a), "+v"(b));
#endif
}

// ---------- fused input prep: casts + scale folding, one launch ----------
// blocks [0,4096): x -> xb ; [4096,5632): w_qkv -> wqb (Q rows scaled)
// [5632,6144): w_o -> wob ; [6144,6156): b_qkv scale -> bsc
__global__ void prep_inputs(const float* __restrict__ x, const float* __restrict__ wqkv,
                            const float* __restrict__ bqkv, const float* __restrict__ wo,
                            u16* __restrict__ xb, u16* __restrict__ wqb,
                            u16* __restrict__ wob, float* __restrict__ bsc) {
    int blk = blockIdx.x;
    if (blk < 6144) {
        const float* src; u16* dst; int base; bool qscale = false;
        if (blk < 4096)      { src = x;    dst = xb;  base = blk; }
        else if (blk < 5632) { src = wqkv; dst = wqb; base = blk - 4096; qscale = true; }
        else                 { src = wo;   dst = wob; base = blk - 5632; }
        int i = (base * 256 + threadIdx.x) * 8;
        float sc = 1.0f;
        if (qscale) { int row = i >> 10; if ((row % 192) < 64) sc = QSCALE; }
        float4 a = *(const float4*)(src + i);
        float4 c = *(const float4*)(src + i + 4);
        union { u16 s[8]; u32x4 v; } t;
        t.s[0] = f2bf(a.x * sc); t.s[1] = f2bf(a.y * sc); t.s[2] = f2bf(a.z * sc); t.s[3] = f2bf(a.w * sc);
        t.s[4] = f2bf(c.x * sc); t.s[5] = f2bf(c.y * sc); t.s[6] = f2bf(c.z * sc); t.s[7] = f2bf(c.w * sc);
        *(u32x4*)(dst + i) = t.v;
    } else {
        int i = (blk - 6144) * 256 + threadIdx.x;   // 0..3071
        float sc = ((i % 192) < 64) ? QSCALE : 1.0f;
        bsc[i] = bqkv[i] * sc;
    }
}

// ---------- QKV GEMM  qkv[M,3072] = x[M,K] * w_qkv[3072,K]^T + b ----------
// V-section columns (col%192 in [128,192)) are written TRANSPOSED straight to
// vt[bh][d][s] (one 8B store per lane); Q/K go to qkvb. 16-col groups never
// straddle section boundaries, so the branch is wave-uniform.
// 1-D grid, XCD-aware remap (T1): each XCD owns 8 consecutive m-tiles x all
// 24 n-tiles -> A panel 2 MB = L2-resident per XCD (measured ~13 us combined
// win with gemm_out in R7).
__global__ void gemm_qkv(const u16* __restrict__ A, const u16* __restrict__ Bm,
                         const float* __restrict__ bias, u16* __restrict__ qkvb,
                         u16* __restrict__ vtb) {
    const int K = 1024, N = 3072;
    __shared__ u16 As[128 * 32];
    __shared__ u16 Bs[128 * 32];
    const int tid = threadIdx.x;
    const int lane = tid & 63;
    const int wv = tid >> 6, wr = wv >> 1, wc = wv & 1;
    const int l15 = lane & 15, quad = lane >> 4;
    const int id = blockIdx.x;                 // 0..1535
    const int xcd = id & 7, rr = id >> 3;      // rr: 0..191
    const int m0 = ((xcd << 3) + rr / 24) * 128;
    const int n0 = (rr % 24) * 128;

    f32x4 acc[4][4];
#pragma unroll
    for (int i = 0; i < 4; i++)
#pragma unroll
        for (int j = 0; j < 4; j++) acc[i][j] = (f32x4){0.f, 0.f, 0.f, 0.f};

    const u16* Ab = A + (size_t)m0 * K;
    const u16* Bb = Bm + (size_t)n0 * K;
    const int srow = tid >> 2;
    const int sc8 = (tid & 3) * 8;

    for (int k0 = 0; k0 < K; k0 += 32) {
#pragma unroll
        for (int i = 0; i < 2; i++) {
            int row = i * 64 + srow;
            gld_lds16(Ab + (size_t)row * K + k0 + sc8, (char*)As + (size_t)(i * 256 + tid) * 16);
            gld_lds16(Bb + (size_t)row * K + k0 + sc8, (char*)Bs + (size_t)(i * 256 + tid) * 16);
        }
        __syncthreads();
        short8 af[4], bf8[4];
#pragma unroll
        for (int mi = 0; mi < 4; mi++)
            af[mi] = *(const short8*)(As + (wr * 64 + mi * 16 + l15) * 32 + quad * 8);
#pragma unroll
        for (int ni = 0; ni < 4; ni++)
            bf8[ni] = *(const short8*)(Bs + (wc * 64 + ni * 16 + l15) * 32 + quad * 8);
#pragma unroll
        for (int mi = 0; mi < 4; mi++)
#pragma unroll
            for (int ni = 0; ni < 4; ni++)
                acc[mi][ni] = __builtin_amdgcn_mfma_f32_16x16x32_bf16(af[mi], bf8[ni], acc[mi][ni], 0, 0, 0);
        __syncthreads();
    }

#pragma unroll
    for (int mi = 0; mi < 4; mi++) {
        int row_b = m0 + wr * 64 + mi * 16 + quad * 4;
#pragma unroll
        for (int ni = 0; ni < 4; ni++) {
            int c0 = n0 + wc * 64 + ni * 16;          // group base (16-aligned)
            int sec0 = c0 % 192;                       // section offset, wave-uniform
            float bv = bias[c0 + l15];
            float v0 = acc[mi][ni][0] + bv;
            float v1 = acc[mi][ni][1] + bv;
            float v2 = acc[mi][ni][2] + bv;
            float v3 = acc[mi][ni][3] + bv;
            if (sec0 >= 128) {
                // V element: transpose-store to vt[bh][d][s], 4 consecutive s
                int hh = c0 / 192;
                int b = row_b >> 11;
                int s = row_b & 2047;
                int d = sec0 - 128 + l15;
                u32 lo = (u32)f2bf(v0) | ((u32)f2bf(v1) << 16);
                u32 hi = (u32)f2bf(v2) | ((u32)f2bf(v3) << 16);
                *(u32x2*)(vtb + ((size_t)((b * 16 + hh) * 64 + d)) * 2048 + s) = (u32x2){lo, hi};
            } else {
                int col = c0 + l15;
                qkvb[(size_t)(row_b + 0) * N + col] = f2bf(v0);
                qkvb[(size_t)(row_b + 1) * N + col] = f2bf(v1);
                qkvb[(size_t)(row_b + 2) * N + col] = f2bf(v2);
                qkvb[(size_t)(row_b + 3) * N + col] = f2bf(v3);
            }
        }
    }
}

// ---------- out GEMM  out[M,1024] = vals2[M,K] * w_o[1024,K]^T + b_o ----------
// 128x64 tiles; 1-D grid with XCD remap: each XCD owns 8 m-tiles x 16 n-tiles
// -> A panel 2 MB + B 2 MB both L2-resident.
__global__ void gemm_out(const u16* __restrict__ A, const u16* __restrict__ Bm,
                         const float* __restrict__ bias, float* __restrict__ C) {
    const int K = 1024, N = 1024;
    __shared__ u16 As[128 * 32];   // 8 KB
    __shared__ u16 Bs[64 * 32];    // 4 KB
    const int tid = threadIdx.x;
    const int lane = tid & 63;
    const int wv = tid >> 6, wr = wv >> 1, wc = wv & 1;
    const int l15 = lane & 15, quad = lane >> 4;
    const int id = blockIdx.x;                 // 0..1023
    const int xcd = id & 7, rr = id >> 3;      // rr: 0..127
    const int m0 = ((xcd << 3) + (rr >> 4)) * 128;
    const int n0 = (rr & 15) * 64;

    f32x4 acc[4][2];
#pragma unroll
    for (int i = 0; i < 4; i++)
#pragma unroll
        for (int j = 0; j < 2; j++) acc[i][j] = (f32x4){0.f, 0.f, 0.f, 0.f};

    const u16* Ab = A + (size_t)m0 * K;
    const u16* Bb = Bm + (size_t)n0 * K;
    const int srow = tid >> 2;
    const int sc8 = (tid & 3) * 8;

    for (int k0 = 0; k0 < K; k0 += 32) {
#pragma unroll
        for (int i = 0; i < 2; i++)
            gld_lds16(Ab + (size_t)(i * 64 + srow) * K + k0 + sc8, (char*)As + (size_t)(i * 256 + tid) * 16);
        gld_lds16(Bb + (size_t)srow * K + k0 + sc8, (char*)Bs + (size_t)tid * 16);
        __syncthreads();
        short8 af[4], bf8[2];
#pragma unroll
        for (int mi = 0; mi < 4; mi++)
            af[mi] = *(const short8*)(As + (wr * 64 + mi * 16 + l15) * 32 + quad * 8);
#pragma unroll
        for (int ni = 0; ni < 2; ni++)
            bf8[ni] = *(const short8*)(Bs + (wc * 32 + ni * 16 + l15) * 32 + quad * 8);
#pragma unroll
        for (int mi = 0; mi < 4; mi++)
#pragma unroll
            for (int ni = 0; ni < 2; ni++)
                acc[mi][ni] = __builtin_amdgcn_mfma_f32_16x16x32_bf16(af[mi], bf8[ni], acc[mi][ni], 0, 0, 0);
        __syncthreads();
    }

#pragma unroll
    for (int mi = 0; mi < 4; mi++) {
        int row_b = m0 + wr * 64 + mi * 16 + quad * 4;
#pragma unroll
        for (int ni = 0; ni < 2; ni++) {
            int col = n0 + wc * 32 + ni * 16 + l15;
            float bv = bias[col];
#pragma unroll
            for (int r = 0; r < 4; r++)
                C[(size_t)(row_b + r) * N + col] = acc[mi][ni][r] + bv;
        }
    }
}

// ---------- flash attention (round-10 = round-8 core, the measured-best 79.4 us) ----------
// 16x16 MFMA, in-register P via permlane swaps, double-buffered K/Vt staged by
// global_load_lds with 128B-coalesced sources (linear LDS dest + pre-swizzled
// source granule), one barrier per tile, XCD-aware block remap, setprio around
// MFMA clusters.  (R7's fragment-ordered LDS regressed: it halved the staging
// coalescing (16 rows x 64 B vs 8 rows x 128 B) and the longer prefetch
// completion dominated the saved VALU.  Reverted.)
__launch_bounds__(256, 4)
__global__ void flash_attn(const u16* __restrict__ qkv, const u16* __restrict__ vt,
                           u16* __restrict__ vals2) {
    __shared__ u16 Ks[2][64 * 64];   // 2 x 8 KB: 64 keys x 64 d (swizzled)
    __shared__ u16 Vts[2][64 * 64];  // 2 x 8 KB: 64 d x 64 keys (swizzled)

    const int tid = threadIdx.x;
    const int lane = tid & 63, wv = tid >> 6;
    const int l15 = lane & 15, quad = lane >> 4;
    const int e7 = (l15 & 7) * 8;          // u16-unit XOR for swizzled reads
    // XCD-aware decode of the 1-D block id
    const int id = blockIdx.x;
    const int m = id >> 3;
    const int bh = ((id & 7) << 3) + (m >> 4);
    const int s0 = (m & 15) << 7;
    const int b = bh >> 4, h = bh & 15;

    // Q fragments in registers (q rows pre-scaled by log2e/8 at cast time)
    short8 qf[2][2];
    const u16* qbase = qkv + (size_t)(b * 2048 + s0 + wv * 32) * 3072 + h * 192;
#pragma unroll
    for (int qi = 0; qi < 2; qi++)
#pragma unroll
        for (int ks = 0; ks < 2; ks++)
            qf[qi][ks] = *(const short8*)(qbase + (size_t)(qi * 16 + l15) * 3072 + ks * 32 + quad * 8);

    f32x4 o_acc[2][4];
    f32x4 sum_acc[2];
#pragma unroll
    for (int qi = 0; qi < 2; qi++) {
        sum_acc[qi] = (f32x4){0.f, 0.f, 0.f, 0.f};
#pragma unroll
        for (int nd = 0; nd < 4; nd++) o_acc[qi][nd] = (f32x4){0.f, 0.f, 0.f, 0.f};
    }

    const u16* kg = qkv + (size_t)(b * 2048) * 3072 + h * 192 + 64;
    const u16* vg = vt + (size_t)bh * 64 * 2048;

    // staging geometry: chunk j covers rows j*32 + wv*8 + (lane>>3);
    // physical granule lane&7 must hold logical granule (lane&7)^(row&7).
    const int lrow = lane >> 3;            // row within the wave's 8-row slab
    const int lgr  = (lane & 7) ^ lrow;    // pre-swizzled logical granule
    const int r0   = wv * 8 + lrow;        // chunk-0 row (chunk-1 = +32)

    const short8 ones = (short8){0x3F80, 0x3F80, 0x3F80, 0x3F80, 0x3F80, 0x3F80, 0x3F80, 0x3F80};

    // prologue: stage tile 0 into buffer 0
#pragma unroll
    for (int j = 0; j < 2; j++) {
        int row = j * 32 + r0;
        gld_lds16(kg + (size_t)row * 3072 + lgr * 8, (char*)&Ks[0][0] + (size_t)(j * 256 + tid) * 16);
        gld_lds16(vg + (size_t)row * 2048 + lgr * 8, (char*)&Vts[0][0] + (size_t)(j * 256 + tid) * 16);
    }
    __syncthreads();

    int cur = 0;
    for (int kb = 0; kb < 2048; kb += 64) {
        // prefetch next tile into the other buffer (hidden under compute)
        if (kb + 64 < 2048) {
            int nb = cur ^ 1;
#pragma unroll
            for (int j = 0; j < 2; j++) {
                int row = j * 32 + r0;
                gld_lds16(kg + (size_t)(kb + 64 + row) * 3072 + lgr * 8,
                          (char*)&Ks[nb][0] + (size_t)(j * 256 + tid) * 16);
                gld_lds16(vg + (size_t)row * 2048 + kb + 64 + lgr * 8,
                          (char*)&Vts[nb][0] + (size_t)(j * 256 + tid) * 16);
            }
        }

        // S^T = K * Q^T : s_acc[ki][qi] -> key = ki*16+quad*4+r, q = qi*16+l15
        f32x4 s_acc[4][2];
#pragma unroll
        for (int ki = 0; ki < 4; ki++)
#pragma unroll
            for (int qi = 0; qi < 2; qi++) s_acc[ki][qi] = (f32x4){0.f, 0.f, 0.f, 0.f};
        __builtin_amdgcn_s_setprio(1);
#pragma unroll
        for (int ki = 0; ki < 4; ki++) {
#pragma unroll
            for (int ks = 0; ks < 2; ks++) {
                short8 kf = *(const short8*)(&Ks[cur][0] + (ki * 16 + l15) * 64 + ((ks * 32 + quad * 8) ^ e7));
#pragma unroll
                for (int qi = 0; qi < 2; qi++)
                    s_acc[ki][qi] = __builtin_amdgcn_mfma_f32_16x16x32_bf16(kf, qf[qi][ks], s_acc[ki][qi], 0, 0, 0);
            }
        }
        __builtin_amdgcn_s_setprio(0);

        // P = exp2(S^T) -> pack bf16 pairs -> permlane swaps build PV A-frags
        // in-register (no LDS round-trip).
        short8 ap[2][2];   // [qi][c]: P[q=l15][key=c*32+quad*8+0..7]
#pragma unroll
        for (int c = 0; c < 2; c++)
#pragma unroll
            for (int qi = 0; qi < 2; qi++) {
                u32 w0 = pack_bf16_trunc(__builtin_amdgcn_exp2f(s_acc[2 * c][qi][0]),
                                         __builtin_amdgcn_exp2f(s_acc[2 * c][qi][1]));
                u32 w1 = pack_bf16_trunc(__builtin_amdgcn_exp2f(s_acc[2 * c][qi][2]),
                                         __builtin_amdgcn_exp2f(s_acc[2 * c][qi][3]));
                u32 w2 = pack_bf16_trunc(__builtin_amdgcn_exp2f(s_acc[2 * c + 1][qi][0]),
                                         __builtin_amdgcn_exp2f(s_acc[2 * c + 1][qi][1]));
                u32 w3 = pack_bf16_trunc(__builtin_amdgcn_exp2f(s_acc[2 * c + 1][qi][2]),
                                         __builtin_amdgcn_exp2f(s_acc[2 * c + 1][qi][3]));
                plswap32(w0, w2);
                plswap32(w1, w3);
                plswap16(w0, w2);
                plswap16(w1, w3);
                u32x4 wf = (u32x4){w0, w1, w2, w3};
                ap[qi][c] = __builtin_bit_cast(short8, wf);
            }

        // PV over 2 chunks of 32 keys; denominator via ones-column MFMA
#pragma unroll
        for (int c = 0; c < 2; c++) {
#pragma unroll
            for (int qi = 0; qi < 2; qi++)
                sum_acc[qi] = __builtin_amdgcn_mfma_f32_16x16x32_bf16(ap[qi][c], ones, sum_acc[qi], 0, 0, 0);
            __builtin_amdgcn_s_setprio(1);
#pragma unroll
            for (int nd = 0; nd < 4; nd++) {
                short8 bv = *(const short8*)(&Vts[cur][0] + (nd * 16 + l15) * 64 + ((c * 32 + quad * 8) ^ e7));
#pragma unroll
                for (int qi = 0; qi < 2; qi++)
                    o_acc[qi][nd] = __builtin_amdgcn_mfma_f32_16x16x32_bf16(ap[qi][c], bv, o_acc[qi][nd], 0, 0, 0);
            }
            __builtin_amdgcn_s_setprio(0);
        }

        __syncthreads();   // implicit vmcnt(0): prefetch complete; all reads of [cur] done
        cur ^= 1;
    }

    // epilogue: normalize (sum is broadcast across l15 by the ones-MFMA) and
    // write vals2 in the no-head-transpose reshape layout.
#pragma unroll
    for (int qi = 0; qi < 2; qi++) {
        f32x4 inv;
#pragma unroll
        for (int r = 0; r < 4; r++) inv[r] = 1.0f / sum_acc[qi][r];
#pragma unroll
        for (int nd = 0; nd < 4; nd++) {
            int d = nd * 16 + l15;
#pragma unroll
            for (int r = 0; r < 4; r++) {
                int s = s0 + wv * 32 + qi * 16 + quad * 4 + r;
                size_t row2 = (size_t)(b * 2048 + h * 128 + (s >> 4));
                int col2 = ((s & 15) << 6) + d;
                vals2[row2 * 1024 + col2] = f2bf(o_acc[qi][nd][r] * inv[r]);
            }
        }
    }
}

// ---------- launch ----------
extern "C" void kernel_launch(void* const* d_in, const int* in_sizes, int n_in,
                              void* d_out, int out_size, void* d_ws, size_t ws_size,
                              hipStream_t stream) {
    (void)in_sizes; (void)n_in; (void)out_size; (void)ws_size;
    const float* x      = (const float*)d_in[0];   // (4,2048,1024)
    const float* w_qkv  = (const float*)d_in[1];   // (3072,1024)
    const float* b_qkv  = (const float*)d_in[2];   // (3072,)
    const float* w_o    = (const float*)d_in[3];   // (1024,1024)
    const float* b_o    = (const float*)d_in[4];   // (1024,)
    float* out = (float*)d_out;

    char* ws = (char*)d_ws;
    u16* xb   = (u16*)(ws);                          // 16 MB  x bf16 (8192x1024)
    u16* wqb  = (u16*)(ws + 16777216);               // 6 MB   w_qkv bf16 (Q rows pre-scaled)
    u16* wob  = (u16*)(ws + 23068672);               // 2 MB   w_o bf16
    u16* qkvb = (u16*)(ws + 25165824);               // 48 MB  qkv bf16 (Q,K sections only)
    u16* vtb  = (u16*)(ws + 75497472);               // 16 MB  V^T bf16 (64bh x 64d x 2048s)
    u16* v2b  = (u16*)(ws + 92274688);               // 16 MB  vals2 bf16 (8192x1024)
    // scaled b_qkv lives in the v2b region: consumed by gemm_qkv, which
    // completes (same stream) before flash_attn overwrites v2b.
    float* bsc = (float*)(ws + 92274688);

    prep_inputs<<<6156, 256, 0, stream>>>(x, w_qkv, b_qkv, w_o, xb, wqb, wob, bsc);

    // qkv = x * w_qkv^T + b_qkv ; V section written transposed to vtb (XCD remap)
    gemm_qkv<<<1536, 256, 0, stream>>>(xb, wqb, bsc, qkvb, vtb);

    // attention -> vals2 (bf16, quirky reshape layout); 1-D grid, XCD-aware remap
    flash_attn<<<1024, 256, 0, stream>>>(qkvb, vtb, v2b);

    // out = vals2 * w_o^T + b_o   (M=8192, N=1024, K=1024), fp32 out (XCD remap)
    gemm_out<<<1024, 256, 0, stream>>>(v2b, wob, b_o, out);
}

// Round 9
// 241.686 us; speedup vs baseline: 1.1744x; 1.0848x over previous
//
#include <hip/hip_runtime.h>
#include <stdint.h>
#include <stddef.h>

#define DEVINL __device__ __forceinline__

typedef unsigned short u16;
typedef unsigned int u32;
typedef __attribute__((ext_vector_type(8))) short short8;
typedef __attribute__((ext_vector_type(4))) float f32x4;
typedef __attribute__((ext_vector_type(4))) u32 u32x4;
typedef __attribute__((ext_vector_type(2))) u32 u32x2;

// log2(e)/8 : folded into W_q / b_q so flash's exp2 needs no multiply
#define QSCALE 0.18033688011112042f

// ---------- helpers ----------
DEVINL u16 f2bf(float f) {
    u32 u = __builtin_bit_cast(u32, f);
    u32 r = (u + 0x7fffu + ((u >> 16) & 1u)) >> 16;   // RNE
    return (u16)r;
}

DEVINL void gld_lds16(const void* g, void* l) {
    __builtin_amdgcn_global_load_lds(
        (__attribute__((address_space(1))) u32*)(uintptr_t)g,
        (__attribute__((address_space(3))) u32*)l, 16, 0, 0);
}

// pack two fp32 -> bf16x2 by truncation (bias cancels: denominator sums the same bf16 P)
DEVINL u32 pack_bf16_trunc(float lo, float hi) {
    return __builtin_amdgcn_perm(__builtin_bit_cast(u32, hi),
                                 __builtin_bit_cast(u32, lo), 0x07060302u);
}

// cross-lane half swaps (gfx950): both outputs are used.
DEVINL void plswap32(u32 &a, u32 &b) {
#if __has_builtin(__builtin_amdgcn_permlane32_swap)
    u32x2 r = __builtin_amdgcn_permlane32_swap(a, b, false, false);
    a = r[0]; b = r[1];
#else
    asm("v_permlane32_swap_b32 %0, %1" : "+v"(a), "+v"(b));
#endif
}
DEVINL void plswap16(u32 &a, u32 &b) {
#if __has_builtin(__builtin_amdgcn_permlane16_swap)
    u32x2 r = __builtin_amdgcn_permlane16_swap(a, b, false, false);
    a = r[0]; b = r[1];
#else
    asm("v_permlane16_swap_b32 %0, %1" : "+v"(a), "+v"(b));
#endif
}

// ---------- fused input prep: casts + scale folding, one launch ----------
// blocks [0,4096): x -> xb ; [4096,5632): w_qkv -> wqb (Q rows scaled)
// [5632,6144): w_o -> wob ; [6144,6156): b_qkv scale -> bsc
__global__ void prep_inputs(const float* __restrict__ x, const float* __restrict__ wqkv,
                            const float* __restrict__ bqkv, const float* __restrict__ wo,
                            u16* __restrict__ xb, u16* __restrict__ wqb,
                            u16* __restrict__ wob, float* __restrict__ bsc) {
    int blk = blockIdx.x;
    if (blk < 6144) {
        const float* src; u16* dst; int base; bool qscale = false;
        if (blk < 4096)      { src = x;    dst = xb;  base = blk; }
        else if (blk < 5632) { src = wqkv; dst = wqb; base = blk - 4096; qscale = true; }
        else                 { src = wo;   dst = wob; base = blk - 5632; }
        int i = (base * 256 + threadIdx.x) * 8;
        float sc = 1.0f;
        if (qscale) { int row = i >> 10; if ((row % 192) < 64) sc = QSCALE; }
        float4 a = *(const float4*)(src + i);
        float4 c = *(const float4*)(src + i + 4);
        union { u16 s[8]; u32x4 v; } t;
        t.s[0] = f2bf(a.x * sc); t.s[1] = f2bf(a.y * sc); t.s[2] = f2bf(a.z * sc); t.s[3] = f2bf(a.w * sc);
        t.s[4] = f2bf(c.x * sc); t.s[5] = f2bf(c.y * sc); t.s[6] = f2bf(c.z * sc); t.s[7] = f2bf(c.w * sc);
        *(u32x4*)(dst + i) = t.v;
    } else {
        int i = (blk - 6144) * 256 + threadIdx.x;   // 0..3071
        float sc = ((i % 192) < 64) ? QSCALE : 1.0f;
        bsc[i] = bqkv[i] * sc;
    }
}

// ---------- QKV GEMM  qkv[M,3072] = x[M,K] * w_qkv[3072,K]^T + b ----------
// Round-9: LDS tiles now use flash's verified-zero-conflict geometry: BK=64
// (128 B rows, 8 granules), staging via global_load_lds with linear dest and
// pre-swizzled source granule lgr=(lane&7)^(row&7); fragment reads at
// row*64 + ((ks*32+quad*8) ^ (l15&7)*8).  Old [128][32] layout (64 B rows)
// had lanes of equal row-parity on one bank quartet -> 6.29e6 conflict cycles
// (4 cyc per b128, MfmaUtil 26%).  BK=64 also halves barrier count (16 iters).
// V-section columns (col%192 in [128,192)) are written TRANSPOSED straight to
// vt[bh][d][s]; Q/K go to qkvb.  16-col groups never straddle sections.
// 1-D grid, XCD-aware remap (T1): each XCD owns 8 consecutive m-tiles x all
// 24 n-tiles -> A panel 2 MB = L2-resident per XCD.
__global__ void gemm_qkv(const u16* __restrict__ A, const u16* __restrict__ Bm,
                         const float* __restrict__ bias, u16* __restrict__ qkvb,
                         u16* __restrict__ vtb) {
    const int K = 1024, N = 3072;
    __shared__ u16 As[128 * 64];   // 16 KB: 128 rows x 64 k (swizzled granules)
    __shared__ u16 Bs[128 * 64];   // 16 KB
    const int tid = threadIdx.x;
    const int lane = tid & 63;
    const int wv = tid >> 6, wr = wv >> 1, wc = wv & 1;
    const int l15 = lane & 15, quad = lane >> 4;
    const int e7 = (l15 & 7) * 8;              // u16-unit XOR for swizzled reads
    const int id = blockIdx.x;                 // 0..1535
    const int xcd = id & 7, rr = id >> 3;      // rr: 0..191
    const int m0 = ((xcd << 3) + rr / 24) * 128;
    const int n0 = (rr % 24) * 128;

    f32x4 acc[4][4];
#pragma unroll
    for (int i = 0; i < 4; i++)
#pragma unroll
        for (int j = 0; j < 4; j++) acc[i][j] = (f32x4){0.f, 0.f, 0.f, 0.f};

    const u16* Ab = A + (size_t)m0 * K;
    const u16* Bb = Bm + (size_t)n0 * K;
    // staging: chunk j covers rows j*32 + wv*8 + (lane>>3); physical granule
    // lane&7 holds logical granule (lane&7)^(row&7)  [flash-verified pattern]
    const int lrow = lane >> 3;
    const int lgr  = (lane & 7) ^ lrow;
    const int r0   = wv * 8 + lrow;

    for (int k0 = 0; k0 < K; k0 += 64) {
#pragma unroll
        for (int j = 0; j < 4; j++) {
            int row = j * 32 + r0;
            gld_lds16(Ab + (size_t)row * K + k0 + lgr * 8, (char*)As + (size_t)(j * 256 + tid) * 16);
            gld_lds16(Bb + (size_t)row * K + k0 + lgr * 8, (char*)Bs + (size_t)(j * 256 + tid) * 16);
        }
        __syncthreads();
#pragma unroll
        for (int ks = 0; ks < 2; ks++) {
            short8 af[4], bf8[4];
#pragma unroll
            for (int mi = 0; mi < 4; mi++)
                af[mi] = *(const short8*)(As + (wr * 64 + mi * 16 + l15) * 64 + ((ks * 32 + quad * 8) ^ e7));
#pragma unroll
            for (int ni = 0; ni < 4; ni++)
                bf8[ni] = *(const short8*)(Bs + (wc * 64 + ni * 16 + l15) * 64 + ((ks * 32 + quad * 8) ^ e7));
#pragma unroll
            for (int mi = 0; mi < 4; mi++)
#pragma unroll
                for (int ni = 0; ni < 4; ni++)
                    acc[mi][ni] = __builtin_amdgcn_mfma_f32_16x16x32_bf16(af[mi], bf8[ni], acc[mi][ni], 0, 0, 0);
        }
        __syncthreads();
    }

#pragma unroll
    for (int mi = 0; mi < 4; mi++) {
        int row_b = m0 + wr * 64 + mi * 16 + quad * 4;
#pragma unroll
        for (int ni = 0; ni < 4; ni++) {
            int c0 = n0 + wc * 64 + ni * 16;          // group base (16-aligned)
            int sec0 = c0 % 192;                       // section offset, wave-uniform
            float bv = bias[c0 + l15];
            float v0 = acc[mi][ni][0] + bv;
            float v1 = acc[mi][ni][1] + bv;
            float v2 = acc[mi][ni][2] + bv;
            float v3 = acc[mi][ni][3] + bv;
            if (sec0 >= 128) {
                // V element: transpose-store to vt[bh][d][s], 4 consecutive s
                int hh = c0 / 192;
                int b = row_b >> 11;
                int s = row_b & 2047;
                int d = sec0 - 128 + l15;
                u32 lo = (u32)f2bf(v0) | ((u32)f2bf(v1) << 16);
                u32 hi = (u32)f2bf(v2) | ((u32)f2bf(v3) << 16);
                *(u32x2*)(vtb + ((size_t)((b * 16 + hh) * 64 + d)) * 2048 + s) = (u32x2){lo, hi};
            } else {
                int col = c0 + l15;
                qkvb[(size_t)(row_b + 0) * N + col] = f2bf(v0);
                qkvb[(size_t)(row_b + 1) * N + col] = f2bf(v1);
                qkvb[(size_t)(row_b + 2) * N + col] = f2bf(v2);
                qkvb[(size_t)(row_b + 3) * N + col] = f2bf(v3);
            }
        }
    }
}

// ---------- out GEMM  out[M,1024] = vals2[M,K] * w_o[1024,K]^T + b_o ----------
// 128x64 tiles; BK=64 flash-pattern LDS (zero-conflict), 1-D grid with XCD
// remap: each XCD owns 8 m-tiles x 16 n-tiles -> A/B panels L2-resident.
__global__ void gemm_out(const u16* __restrict__ A, const u16* __restrict__ Bm,
                         const float* __restrict__ bias, float* __restrict__ C) {
    const int K = 1024, N = 1024;
    __shared__ u16 As[128 * 64];   // 16 KB
    __shared__ u16 Bs[64 * 64];    // 8 KB
    const int tid = threadIdx.x;
    const int lane = tid & 63;
    const int wv = tid >> 6, wr = wv >> 1, wc = wv & 1;
    const int l15 = lane & 15, quad = lane >> 4;
    const int e7 = (l15 & 7) * 8;
    const int id = blockIdx.x;                 // 0..1023
    const int xcd = id & 7, rr = id >> 3;      // rr: 0..127
    const int m0 = ((xcd << 3) + (rr >> 4)) * 128;
    const int n0 = (rr & 15) * 64;

    f32x4 acc[4][2];
#pragma unroll
    for (int i = 0; i < 4; i++)
#pragma unroll
        for (int j = 0; j < 2; j++) acc[i][j] = (f32x4){0.f, 0.f, 0.f, 0.f};

    const u16* Ab = A + (size_t)m0 * K;
    const u16* Bb = Bm + (size_t)n0 * K;
    const int lrow = lane >> 3;
    const int lgr  = (lane & 7) ^ lrow;
    const int r0   = wv * 8 + lrow;

    for (int k0 = 0; k0 < K; k0 += 64) {
#pragma unroll
        for (int j = 0; j < 4; j++)
            gld_lds16(Ab + (size_t)(j * 32 + r0) * K + k0 + lgr * 8,
                      (char*)As + (size_t)(j * 256 + tid) * 16);
#pragma unroll
        for (int j = 0; j < 2; j++)
            gld_lds16(Bb + (size_t)(j * 32 + r0) * K + k0 + lgr * 8,
                      (char*)Bs + (size_t)(j * 256 + tid) * 16);
        __syncthreads();
#pragma unroll
        for (int ks = 0; ks < 2; ks++) {
            short8 af[4], bf8[2];
#pragma unroll
            for (int mi = 0; mi < 4; mi++)
                af[mi] = *(const short8*)(As + (wr * 64 + mi * 16 + l15) * 64 + ((ks * 32 + quad * 8) ^ e7));
#pragma unroll
            for (int ni = 0; ni < 2; ni++)
                bf8[ni] = *(const short8*)(Bs + (wc * 32 + ni * 16 + l15) * 64 + ((ks * 32 + quad * 8) ^ e7));
#pragma unroll
            for (int mi = 0; mi < 4; mi++)
#pragma unroll
                for (int ni = 0; ni < 2; ni++)
                    acc[mi][ni] = __builtin_amdgcn_mfma_f32_16x16x32_bf16(af[mi], bf8[ni], acc[mi][ni], 0, 0, 0);
        }
        __syncthreads();
    }

#pragma unroll
    for (int mi = 0; mi < 4; mi++) {
        int row_b = m0 + wr * 64 + mi * 16 + quad * 4;
#pragma unroll
        for (int ni = 0; ni < 2; ni++) {
            int col = n0 + wc * 32 + ni * 16 + l15;
            float bv = bias[col];
#pragma unroll
            for (int r = 0; r < 4; r++)
                C[(size_t)(row_b + r) * N + col] = acc[mi][ni][r] + bv;
        }
    }
}

// ---------- flash attention (round-8 core, measured ~79.6 us — unchanged) ----------
// 16x16 MFMA, in-register P via permlane swaps, double-buffered K/Vt staged by
// global_load_lds with 128B-coalesced sources (linear LDS dest + pre-swizzled
// source granule), one barrier per tile, XCD-aware block remap, setprio around
// MFMA clusters.
__launch_bounds__(256, 4)
__global__ void flash_attn(const u16* __restrict__ qkv, const u16* __restrict__ vt,
                           u16* __restrict__ vals2) {
    __shared__ u16 Ks[2][64 * 64];   // 2 x 8 KB: 64 keys x 64 d (swizzled)
    __shared__ u16 Vts[2][64 * 64];  // 2 x 8 KB: 64 d x 64 keys (swizzled)

    const int tid = threadIdx.x;
    const int lane = tid & 63, wv = tid >> 6;
    const int l15 = lane & 15, quad = lane >> 4;
    const int e7 = (l15 & 7) * 8;          // u16-unit XOR for swizzled reads
    // XCD-aware decode of the 1-D block id
    const int id = blockIdx.x;
    const int m = id >> 3;
    const int bh = ((id & 7) << 3) + (m >> 4);
    const int s0 = (m & 15) << 7;
    const int b = bh >> 4, h = bh & 15;

    // Q fragments in registers (q rows pre-scaled by log2e/8 at cast time)
    short8 qf[2][2];
    const u16* qbase = qkv + (size_t)(b * 2048 + s0 + wv * 32) * 3072 + h * 192;
#pragma unroll
    for (int qi = 0; qi < 2; qi++)
#pragma unroll
        for (int ks = 0; ks < 2; ks++)
            qf[qi][ks] = *(const short8*)(qbase + (size_t)(qi * 16 + l15) * 3072 + ks * 32 + quad * 8);

    f32x4 o_acc[2][4];
    f32x4 sum_acc[2];
#pragma unroll
    for (int qi = 0; qi < 2; qi++) {
        sum_acc[qi] = (f32x4){0.f, 0.f, 0.f, 0.f};
#pragma unroll
        for (int nd = 0; nd < 4; nd++) o_acc[qi][nd] = (f32x4){0.f, 0.f, 0.f, 0.f};
    }

    const u16* kg = qkv + (size_t)(b * 2048) * 3072 + h * 192 + 64;
    const u16* vg = vt + (size_t)bh * 64 * 2048;

    // staging geometry: chunk j covers rows j*32 + wv*8 + (lane>>3);
    // physical granule lane&7 must hold logical granule (lane&7)^(row&7).
    const int lrow = lane >> 3;            // row within the wave's 8-row slab
    const int lgr  = (lane & 7) ^ lrow;    // pre-swizzled logical granule
    const int r0   = wv * 8 + lrow;        // chunk-0 row (chunk-1 = +32)

    const short8 ones = (short8){0x3F80, 0x3F80, 0x3F80, 0x3F80, 0x3F80, 0x3F80, 0x3F80, 0x3F80};

    // prologue: stage tile 0 into buffer 0
#pragma unroll
    for (int j = 0; j < 2; j++) {
        int row = j * 32 + r0;
        gld_lds16(kg + (size_t)row * 3072 + lgr * 8, (char*)&Ks[0][0] + (size_t)(j * 256 + tid) * 16);
        gld_lds16(vg + (size_t)row * 2048 + lgr * 8, (char*)&Vts[0][0] + (size_t)(j * 256 + tid) * 16);
    }
    __syncthreads();

    int cur = 0;
    for (int kb = 0; kb < 2048; kb += 64) {
        // prefetch next tile into the other buffer (hidden under compute)
        if (kb + 64 < 2048) {
            int nb = cur ^ 1;
#pragma unroll
            for (int j = 0; j < 2; j++) {
                int row = j * 32 + r0;
                gld_lds16(kg + (size_t)(kb + 64 + row) * 3072 + lgr * 8,
                          (char*)&Ks[nb][0] + (size_t)(j * 256 + tid) * 16);
                gld_lds16(vg + (size_t)row * 2048 + kb + 64 + lgr * 8,
                          (char*)&Vts[nb][0] + (size_t)(j * 256 + tid) * 16);
            }
        }

        // S^T = K * Q^T : s_acc[ki][qi] -> key = ki*16+quad*4+r, q = qi*16+l15
        f32x4 s_acc[4][2];
#pragma unroll
        for (int ki = 0; ki < 4; ki++)
#pragma unroll
            for (int qi = 0; qi < 2; qi++) s_acc[ki][qi] = (f32x4){0.f, 0.f, 0.f, 0.f};
        __builtin_amdgcn_s_setprio(1);
#pragma unroll
        for (int ki = 0; ki < 4; ki++) {
#pragma unroll
            for (int ks = 0; ks < 2; ks++) {
                short8 kf = *(const short8*)(&Ks[cur][0] + (ki * 16 + l15) * 64 + ((ks * 32 + quad * 8) ^ e7));
#pragma unroll
                for (int qi = 0; qi < 2; qi++)
                    s_acc[ki][qi] = __builtin_amdgcn_mfma_f32_16x16x32_bf16(kf, qf[qi][ks], s_acc[ki][qi], 0, 0, 0);
            }
        }
        __builtin_amdgcn_s_setprio(0);

        // P = exp2(S^T) -> pack bf16 pairs -> permlane swaps build PV A-frags
        // in-register (no LDS round-trip).
        short8 ap[2][2];   // [qi][c]: P[q=l15][key=c*32+quad*8+0..7]
#pragma unroll
        for (int c = 0; c < 2; c++)
#pragma unroll
            for (int qi = 0; qi < 2; qi++) {
                u32 w0 = pack_bf16_trunc(__builtin_amdgcn_exp2f(s_acc[2 * c][qi][0]),
                                         __builtin_amdgcn_exp2f(s_acc[2 * c][qi][1]));
                u32 w1 = pack_bf16_trunc(__builtin_amdgcn_exp2f(s_acc[2 * c][qi][2]),
                                         __builtin_amdgcn_exp2f(s_acc[2 * c][qi][3]));
                u32 w2 = pack_bf16_trunc(__builtin_amdgcn_exp2f(s_acc[2 * c + 1][qi][0]),
                                         __builtin_amdgcn_exp2f(s_acc[2 * c + 1][qi][1]));
                u32 w3 = pack_bf16_trunc(__builtin_amdgcn_exp2f(s_acc[2 * c + 1][qi][2]),
                                         __builtin_amdgcn_exp2f(s_acc[2 * c + 1][qi][3]));
                plswap32(w0, w2);
                plswap32(w1, w3);
                plswap16(w0, w2);
                plswap16(w1, w3);
                u32x4 wf = (u32x4){w0, w1, w2, w3};
                ap[qi][c] = __builtin_bit_cast(short8, wf);
            }

        // PV over 2 chunks of 32 keys; denominator via ones-column MFMA
#pragma unroll
        for (int c = 0; c < 2; c++) {
#pragma unroll
            for (int qi = 0; qi < 2; qi++)
                sum_acc[qi] = __builtin_amdgcn_mfma_f32_16x16x32_bf16(ap[qi][c], ones, sum_acc[qi], 0, 0, 0);
            __builtin_amdgcn_s_setprio(1);
#pragma unroll
            for (int nd = 0; nd < 4; nd++) {
                short8 bv = *(const short8*)(&Vts[cur][0] + (nd * 16 + l15) * 64 + ((c * 32 + quad * 8) ^ e7));
#pragma unroll
                for (int qi = 0; qi < 2; qi++)
                    o_acc[qi][nd] = __builtin_amdgcn_mfma_f32_16x16x32_bf16(ap[qi][c], bv, o_acc[qi][nd], 0, 0, 0);
            }
            __builtin_amdgcn_s_setprio(0);
        }

        __syncthreads();   // implicit vmcnt(0): prefetch complete; all reads of [cur] done
        cur ^= 1;
    }

    // epilogue: normalize (sum is broadcast across l15 by the ones-MFMA) and
    // write vals2 in the no-head-transpose reshape layout.
#pragma unroll
    for (int qi = 0; qi < 2; qi++) {
        f32x4 inv;
#pragma unroll
        for (int r = 0; r < 4; r++) inv[r] = 1.0f / sum_acc[qi][r];
#pragma unroll
        for (int nd = 0; nd < 4; nd++) {
            int d = nd * 16 + l15;
#pragma unroll
            for (int r = 0; r < 4; r++) {
                int s = s0 + wv * 32 + qi * 16 + quad * 4 + r;
                size_t row2 = (size_t)(b * 2048 + h * 128 + (s >> 4));
                int col2 = ((s & 15) << 6) + d;
                vals2[row2 * 1024 + col2] = f2bf(o_acc[qi][nd][r] * inv[r]);
            }
        }
    }
}

// ---------- launch ----------
extern "C" void kernel_launch(void* const* d_in, const int* in_sizes, int n_in,
                              void* d_out, int out_size, void* d_ws, size_t ws_size,
                              hipStream_t stream) {
    (void)in_sizes; (void)n_in; (void)out_size; (void)ws_size;
    const float* x      = (const float*)d_in[0];   // (4,2048,1024)
    const float* w_qkv  = (const float*)d_in[1];   // (3072,1024)
    const float* b_qkv  = (const float*)d_in[2];   // (3072,)
    const float* w_o    = (const float*)d_in[3];   // (1024,1024)
    const float* b_o    = (const float*)d_in[4];   // (1024,)
    float* out = (float*)d_out;

    char* ws = (char*)d_ws;
    u16* xb   = (u16*)(ws);                          // 16 MB  x bf16 (8192x1024)
    u16* wqb  = (u16*)(ws + 16777216);               // 6 MB   w_qkv bf16 (Q rows pre-scaled)
    u16* wob  = (u16*)(ws + 23068672);               // 2 MB   w_o bf16
    u16* qkvb = (u16*)(ws + 25165824);               // 48 MB  qkv bf16 (Q,K sections only)
    u16* vtb  = (u16*)(ws + 75497472);               // 16 MB  V^T bf16 (64bh x 64d x 2048s)
    u16* v2b  = (u16*)(ws + 92274688);               // 16 MB  vals2 bf16 (8192x1024)
    // scaled b_qkv lives in the v2b region: consumed by gemm_qkv, which
    // completes (same stream) before flash_attn overwrites v2b.
    float* bsc = (float*)(ws + 92274688);

    prep_inputs<<<6156, 256, 0, stream>>>(x, w_qkv, b_qkv, w_o, xb, wqb, wob, bsc);

    // qkv = x * w_qkv^T + b_qkv ; V section written transposed to vtb (XCD remap)
    gemm_qkv<<<1536, 256, 0, stream>>>(xb, wqb, bsc, qkvb, vtb);

    // attention -> vals2 (bf16, quirky reshape layout); 1-D grid, XCD-aware remap
    flash_attn<<<1024, 256, 0, stream>>>(qkvb, vtb, v2b);

    // out = vals2 * w_o^T + b_o   (M=8192, N=1024, K=1024), fp32 out (XCD remap)
    gemm_out<<<1024, 256, 0, stream>>>(v2b, wob, b_o, out);
}